// Round 1
// 277.414 us; speedup vs baseline: 1.0243x; 1.0243x over previous
//
#include <hip/hip_runtime.h>
#include <hip/hip_bf16.h>

#define N_SEQ 4096
#define DIMM  1536
#define NH    4
#define DK    64
#define HD    256     // NH*DK
#define QK_SCALE 0.125f
#define WSZ   393216  // 1536*256 per weight
#define KSPLIT 8

typedef __bf16 bf16x8 __attribute__((ext_vector_type(8)));
typedef unsigned short u16;
typedef u16   u16x8  __attribute__((ext_vector_type(8)));
typedef u16   u16x4  __attribute__((ext_vector_type(4)));
typedef float f32x4  __attribute__((ext_vector_type(4)));
typedef float f32x16 __attribute__((ext_vector_type(16)));
typedef unsigned int u32x4 __attribute__((ext_vector_type(4)));

__device__ inline float b2f(u16 u){
    union { float f; unsigned int i; } v; v.i = ((unsigned int)u) << 16; return v.f;
}
__device__ inline u16 f2b(float f){
    __bf16 h = (__bf16)f;               // native cvt, RNE
    return __builtin_bit_cast(u16, h);
}
__device__ inline bf16x8 ldfrag(const u16* p){
    return __builtin_bit_cast(bf16x8, *(const u16x8*)p);
}
__device__ inline f32x16 zero16(){
    f32x16 v;
    #pragma unroll
    for (int i = 0; i < 16; ++i) v[i] = 0.f;
    return v;
}
__device__ inline float pair_sum(unsigned int wd){
    union { unsigned int i; float f; } lo, hi;
    lo.i = wd << 16; hi.i = wd & 0xffff0000u;
    return lo.f + hi.f;
}

// ---------------------------------------------------------------------------
// Convert Wq|Wk|Wv (fp32, [k][n]) -> Wt (bf16, TRANSPOSED [n][k]).
// ---------------------------------------------------------------------------
__global__ __launch_bounds__(256) void convwt_kernel(const float* __restrict__ Wq,
    const float* __restrict__ Wk, const float* __restrict__ Wv, u16* __restrict__ Wt){
    int idx = (blockIdx.x * 256 + threadIdx.x) * 8;   // 576 blocks
    int s = idx / WSZ, off = idx % WSZ;
    int n = off / DIMM, k = off % DIMM;
    const float* W = (s == 0) ? Wq : (s == 1 ? Wk : Wv);
    u16x8 o;
    #pragma unroll
    for (int e = 0; e < 8; ++e) o[e] = f2b(W[(size_t)(k + e) * HD + n]);
    *(u16x8*)&Wt[idx] = o;
}

// ---------------------------------------------------------------------------
// fmtab[ad] = #{f in [0,32): cw[f] <= ad}
// ---------------------------------------------------------------------------
__global__ __launch_bounds__(256) void fmtab_kernel(unsigned char* __restrict__ fmt){
    int d = blockIdx.x * 256 + threadIdx.x;           // 16 blocks
    float lg = logf((float)(N_SEQ + 1)) * (1.0f / 32.0f);
    float ad = (float)d;
    int fm = 0;
    for (int f = 0; f < 32; ++f){
        float cw = expf(lg * (float)(f + 1)) - 1.0f;
        fm += (cw <= ad) ? 1 : 0;
    }
    fmt[d] = (unsigned char)fm;
}

// ---------------------------------------------------------------------------
// Suffix-summed relative-position weights (f32 accumulate, bf16 store):
//   WsP[h][fm][d] = sum_{f=fm..31} Wr[f][h*64+d] + sum_{f=32+fm..63} Wr[f][h*64+d]
//   WsM[h][fm][d] = first - second
// Then relP[i][fm] = (q[i]+PB) . WsP[h][fm], relM likewise, via MFMA in attn.
// ---------------------------------------------------------------------------
__global__ __launch_bounds__(256) void wsuf_kernel(const float* __restrict__ Wrel,
    u16* __restrict__ WsP, u16* __restrict__ WsM){
    int t = threadIdx.x;                 // 1 block
    int h = t >> 6, d = t & 63;
    float a1 = 0.f, a2 = 0.f;
    for (int fm = 31; fm >= 0; --fm){
        a1 += Wrel[(size_t)fm * HD + h * DK + d];
        a2 += Wrel[(size_t)(32 + fm) * HD + h * DK + d];
        WsP[(h * 32 + fm) * 64 + d] = f2b(a1 + a2);
        WsM[(h * 32 + fm) * 64 + d] = f2b(a1 - a2);
    }
}

// ---------------------------------------------------------------------------
// Fused QKV (unchanged): one block per (n0, m0); V stored transposed.
// ---------------------------------------------------------------------------
__global__ __launch_bounds__(256) void qkv_kernel(const float* __restrict__ X,
    const u16* __restrict__ Wt,
    u16* __restrict__ Q, u16* __restrict__ K, u16* __restrict__ Vt){
    __shared__ __align__(16) u16 xs[64 * 72];
    __shared__ __align__(16) u16 bs[3 * 64 * 72];
    int n0 = blockIdx.x * 64;
    int m0 = blockIdx.y * 64;
    int t = threadIdx.x;
    int w = t >> 6, lane = t & 63, qd = lane >> 4, l15 = lane & 15;
    f32x4 acc[3][4];
    #pragma unroll
    for (int s = 0; s < 3; ++s)
        #pragma unroll
        for (int nt = 0; nt < 4; ++nt) acc[s][nt] = (f32x4){0,0,0,0};
    for (int k0 = 0; k0 < DIMM; k0 += 64){
        #pragma unroll
        for (int rep = 0; rep < 2; ++rep){
            int vid = rep * 256 + t;
            int r  = vid >> 3;
            int cv = (vid & 7) * 8;
            size_t xi = (size_t)(m0 + r) * DIMM + k0 + cv;
            f32x4 xa = *(const f32x4*)(X + xi), xb = *(const f32x4*)(X + xi + 4);
            u16x8 xv;
            #pragma unroll
            for (int e = 0; e < 4; ++e){ xv[e] = f2b(xa[e]); xv[4 + e] = f2b(xb[e]); }
            *(u16x8*)&xs[r * 72 + cv] = xv;
            #pragma unroll
            for (int s = 0; s < 3; ++s){
                u16x8 wv = *(const u16x8*)&Wt[(size_t)s * WSZ + (size_t)(n0 + r) * DIMM + k0 + cv];
                *(u16x8*)&bs[s * 4608 + r * 72 + cv] = wv;
            }
        }
        __syncthreads();
        bf16x8 a0 = ldfrag(&xs[(w * 16 + l15) * 72 +  0 + qd * 8]);
        bf16x8 a1 = ldfrag(&xs[(w * 16 + l15) * 72 + 32 + qd * 8]);
        #pragma unroll
        for (int s = 0; s < 3; ++s)
            #pragma unroll
            for (int nt = 0; nt < 4; ++nt){
                bf16x8 b0 = ldfrag(&bs[s * 4608 + (nt * 16 + l15) * 72 +  0 + qd * 8]);
                bf16x8 b1 = ldfrag(&bs[s * 4608 + (nt * 16 + l15) * 72 + 32 + qd * 8]);
                acc[s][nt] = __builtin_amdgcn_mfma_f32_16x16x32_bf16(a0, b0, acc[s][nt], 0, 0, 0);
                acc[s][nt] = __builtin_amdgcn_mfma_f32_16x16x32_bf16(a1, b1, acc[s][nt], 0, 0, 0);
            }
        __syncthreads();
    }
    int row0 = m0 + w * 16 + qd * 4;
    #pragma unroll
    for (int nt = 0; nt < 4; ++nt){
        int col = n0 + nt * 16 + l15;
        #pragma unroll
        for (int reg = 0; reg < 4; ++reg){
            Q[(size_t)(row0 + reg) * HD + col] = f2b(acc[0][nt][reg] * QK_SCALE);
            K[(size_t)(row0 + reg) * HD + col] = f2b(acc[1][nt][reg]);
        }
        u16x4 pv;
        #pragma unroll
        for (int reg = 0; reg < 4; ++reg) pv[reg] = f2b(acc[2][nt][reg]);
        *(u16x4*)&Vt[(size_t)col * N_SEQ + row0] = pv;
    }
}

// ---------------------------------------------------------------------------
// Flash attention, restructured: 32x32x16 MFMA, swapped QK^T (S^T = K.Q^T) so
// softmax row i = lane&31 is lane-local; P never round-trips LDS (in-register
// word exchange via shfl_xor(32) builds the PV A-fragment); rel tables built
// by MFMA against suffix-summed weights; defer-max (THR=8) online softmax.
// Block: 4 waves x 32 Q-rows = 128 rows; K-split 8 (j-range 512, 8 tiles).
// ---------------------------------------------------------------------------
__global__ __launch_bounds__(256) void attn_kernel(const u16* __restrict__ Q,
    const u16* __restrict__ Kg, const u16* __restrict__ Vt,
    const u16* __restrict__ WsPg, const u16* __restrict__ WsMg,
    const unsigned char* __restrict__ fmtg,
    const float* __restrict__ CB, const float* __restrict__ PB,
    u16* __restrict__ OpU, float* __restrict__ mpart, float* __restrict__ lpart){
    __shared__ __align__(16) unsigned char smem[39936];
    u16* Ks   = (u16*)(smem);             // [64][72]  main loop
    u16* Vts  = (u16*)(smem + 9216);      // [64][72]  main loop
    u16* Qs   = (u16*)(smem);             // init alias: [128][72]
    u16* relP = (u16*)(smem + 18432);     // [128][34] u16
    u16* relM = (u16*)(smem + 27136);     // [128][34] u16
    unsigned char* fmt = smem + 35840;    // 4096
    u16* WsPs = (u16*)(smem + 18432);     // init alias: [32][72]
    u16* WsMs = (u16*)(smem + 23040);     // init alias: [32][72]

    int i0   = blockIdx.x * 128;
    int h    = blockIdx.y;
    int half = blockIdx.z;                // 0..7
    int bid  = blockIdx.x * NH + h;       // 0..127
    int jbase = half * (N_SEQ / KSPLIT);
    const int NT = (N_SEQ / KSPLIT) / 64; // 8 tiles
    int t = threadIdx.x;
    int w = t >> 6, lane = t & 63, l31 = lane & 31, hbit = lane >> 5;
    int h8 = hbit * 8;
    int i_loc = w * 32 + l31;             // this lane's softmax row (block-local)

    int sr = t >> 3, scv = (t & 7) * 8;
    u16x8 kr0, kr1, vr0, vr1;
    auto LOAD = [&](int j0){
        kr0 = *(const u16x8*)&Kg[(size_t)(j0 + sr)      * HD + h * DK + scv];
        kr1 = *(const u16x8*)&Kg[(size_t)(j0 + 32 + sr) * HD + h * DK + scv];
        vr0 = *(const u16x8*)&Vt[(size_t)(h * 64 + sr)      * N_SEQ + j0 + scv];
        vr1 = *(const u16x8*)&Vt[(size_t)(h * 64 + 32 + sr) * N_SEQ + j0 + scv];
    };
    auto STORE = [&](){
        *(u16x8*)&Ks [(sr)      * 72 + scv] = kr0;
        *(u16x8*)&Ks [(32 + sr) * 72 + scv] = kr1;
        *(u16x8*)&Vts[(sr)      * 72 + scv] = vr0;
        *(u16x8*)&Vts[(32 + sr) * 72 + scv] = vr1;
    };
    LOAD(jbase);

    // ---- init staging: Q rows (raw bf16), Wsuf slices, fmt ----
    #pragma unroll
    for (int rep = 0; rep < 4; ++rep){
        int vid = rep * 256 + t;
        int r  = vid >> 3;
        int cv = (vid & 7) * 8;
        *(u16x8*)&Qs[r * 72 + cv] = *(const u16x8*)&Q[(size_t)(i0 + r) * HD + h * DK + cv];
    }
    {
        int r = t >> 3, cv = (t & 7) * 8;
        *(u16x8*)&WsPs[r * 72 + cv] = *(const u16x8*)&WsPg[(h * 32 + r) * 64 + cv];
        *(u16x8*)&WsMs[r * 72 + cv] = *(const u16x8*)&WsMg[(h * 32 + r) * 64 + cv];
    }
    ((uint4*)fmt)[t] = ((const uint4*)fmtg)[t];
    __syncthreads();

    // ---- build per-lane Q fragments (B-operand layout: col=i=lane&31,
    //      k = hbit*8+e + 16*kc), with content/pos bias folded in ----
    bf16x8 qcF[4], qpF[4];
    #pragma unroll
    for (int kc = 0; kc < 4; ++kc){
        bf16x8 raw = ldfrag(&Qs[i_loc * 72 + kc * 16 + h8]);
        const float* cbp = CB + h * DK + kc * 16 + h8;
        const float* pbp = PB + h * DK + kc * 16 + h8;
        bf16x8 qc, qp;
        #pragma unroll
        for (int e = 0; e < 8; ++e){
            float qf = (float)raw[e];
            qc[e] = (__bf16)(qf + cbp[e]);
            qp[e] = (__bf16)(qf + pbp[e]);
        }
        qcF[kc] = qc; qpF[kc] = qp;
    }

    // ---- rel tables via MFMA: C[fm][i] = Wsuf[fm] . qp[i] ----
    f32x16 rP = zero16(), rM = zero16();
    #pragma unroll
    for (int kc = 0; kc < 4; ++kc){
        bf16x8 aP = ldfrag(&WsPs[l31 * 72 + kc * 16 + h8]);
        bf16x8 aM = ldfrag(&WsMs[l31 * 72 + kc * 16 + h8]);
        rP = __builtin_amdgcn_mfma_f32_32x32x16_bf16(aP, qpF[kc], rP, 0, 0, 0);
        rM = __builtin_amdgcn_mfma_f32_32x32x16_bf16(aM, qpF[kc], rM, 0, 0, 0);
    }
    __syncthreads();   // all LDS reads (Qs, Wsuf) done before overwrites

    // rel store: lane holds col i=lane&31, rows fm=(r&3)+8*(r>>2)+4*hbit
    #pragma unroll
    for (int r = 0; r < 16; ++r){
        int fm = (r & 3) + 8 * (r >> 2) + 4 * hbit;
        relP[i_loc * 34 + fm] = f2b(rP[r]);
        relM[i_loc * 34 + fm] = f2b(rM[r]);
    }
    if (hbit == 0){
        relP[i_loc * 34 + 33] = f2b((rP[0] + rM[0]) * 0.5f);  // d==0: s1 = (P0+M0)/2
        relP[i_loc * 34 + 32] = 0;                            // fm==32: no features
        relM[i_loc * 34 + 32] = 0;
        relM[i_loc * 34 + 33] = 0;
    }
    STORE();           // K/V tile 0 into seg0 (Qs dead)
    __syncthreads();

    // ---- main K-loop ----
    float mrow = -1e30f, lacc = 0.f;
    f32x16 oacc0 = zero16(), oacc1 = zero16();

#define MFMA32(A, B, C) __builtin_amdgcn_mfma_f32_32x32x16_bf16(A, B, C, 0, 0, 0)

#define PACK8(ST, WD) { \
    _Pragma("unroll") \
    for (int q_ = 0; q_ < 8; ++q_){ \
        float pa_ = __expf(ST[2 * q_]     - mrow); \
        float pc_ = __expf(ST[2 * q_ + 1] - mrow); \
        unsigned int wd_ = (unsigned int)f2b(pa_) | ((unsigned int)f2b(pc_) << 16); \
        WD[q_] = wd_; \
        lsum += pair_sum(wd_); \
    } }

#define MKFRAG(DST, WD, ZZ) { \
    unsigned int a0_ = WD[(ZZ) * 4 + 0], a1_ = WD[(ZZ) * 4 + 1]; \
    unsigned int b0_ = WD[(ZZ) * 4 + 2], b1_ = WD[(ZZ) * 4 + 3]; \
    unsigned int xa0_ = (unsigned int)__shfl_xor((int)a0_, 32); \
    unsigned int xa1_ = (unsigned int)__shfl_xor((int)a1_, 32); \
    unsigned int xb0_ = (unsigned int)__shfl_xor((int)b0_, 32); \
    unsigned int xb1_ = (unsigned int)__shfl_xor((int)b1_, 32); \
    u32x4 fw_; \
    fw_[0] = hbit ? xb0_ : a0_; \
    fw_[1] = hbit ? xb1_ : a1_; \
    fw_[2] = hbit ? b0_  : xa0_; \
    fw_[3] = hbit ? b1_  : xa1_; \
    DST = __builtin_bit_cast(bf16x8, fw_); }

#define PVSTEP(PF, COL) { \
    oacc0 = MFMA32(PF, ldfrag(&Vts[(l31)      * 72 + (COL) + h8]), oacc0); \
    oacc1 = MFMA32(PF, ldfrag(&Vts[(32 + l31) * 72 + (COL) + h8]), oacc1); }

    for (int kt = 0; kt < NT; ++kt){
        int j0 = jbase + kt * 64;
        if (kt + 1 < NT) LOAD(j0 + 64);

        // S^T = K . Q^T : st0 = rows j 0..31, st1 = rows j 32..63; col i = lane&31
        f32x16 st0 = zero16(), st1 = zero16();
        #pragma unroll
        for (int kc = 0; kc < 4; ++kc){
            bf16x8 k0 = ldfrag(&Ks[(l31)      * 72 + kc * 16 + h8]);
            bf16x8 k1 = ldfrag(&Ks[(32 + l31) * 72 + kc * 16 + h8]);
            st0 = MFMA32(k0, qcF[kc], st0);
            st1 = MFMA32(k1, qcF[kc], st1);
        }

        // rel merge; lane row i fixed -> fast path is ONE table read per lane
        int D = j0 - i0;
        bool fast = false; int fmU = 0; const u16* tabU = relP;
        if (D >= 128){
            int fa = fmt[D - 127], fb = fmt[D + 63];
            fast = (fa == fb); fmU = fa; tabU = relP;
        } else if (D <= -64){
            int fa = fmt[-D - 63], fb = fmt[-D + 127];
            fast = (fa == fb); fmU = fa; tabU = relM;
        }
        if (fast){
            float relv = b2f(tabU[i_loc * 34 + fmU]);
            #pragma unroll
            for (int r = 0; r < 16; ++r){ st0[r] += relv; st1[r] += relv; }
        } else {
            #pragma unroll
            for (int r = 0; r < 16; ++r){
                int jb = (r & 3) + 8 * (r >> 2) + 4 * hbit;
                {
                    int dd = D + jb - i_loc;
                    int ad = dd < 0 ? -dd : dd;
                    int fm = fmt[ad];
                    const u16* tab = (dd >= 0) ? relP : relM;
                    st0[r] += b2f(tab[i_loc * 34 + ((dd == 0) ? 33 : fm)]);
                }
                {
                    int dd = D + 32 + jb - i_loc;
                    int ad = dd < 0 ? -dd : dd;
                    int fm = fmt[ad];
                    const u16* tab = (dd >= 0) ? relP : relM;
                    st1[r] += b2f(tab[i_loc * 34 + ((dd == 0) ? 33 : fm)]);
                }
            }
        }

        // row max (lane-local + one cross-half shuffle)
        float mx = st0[0];
        #pragma unroll
        for (int r = 1; r < 16; ++r) mx = fmaxf(mx, st0[r]);
        #pragma unroll
        for (int r = 0; r < 16; ++r) mx = fmaxf(mx, st1[r]);
        mx = fmaxf(mx, __shfl_xor(mx, 32));

        // defer-max: rescale only when the bound would be exceeded (THR=8)
        if (!__all(mx - mrow <= 8.0f)){
            float mnew = fmaxf(mrow, mx);
            float alpha = __expf(mrow - mnew);
            mrow = mnew;
            lacc *= alpha;
            #pragma unroll
            for (int r = 0; r < 16; ++r){
                float ar = __shfl(alpha, (r & 3) + 8 * (r >> 2) + 4 * hbit);
                oacc0[r] *= ar; oacc1[r] *= ar;
            }
        }

        // P = exp(S - mrow), packed to bf16 words; l from rounded values
        float lsum = 0.f;
        unsigned int wds0[8], wds1[8];
        PACK8(st0, wds0)
        PACK8(st1, wds1)
        lacc += lsum + __shfl_xor(lsum, 32);

        // in-register transpose to PV A-fragments (rows i = lane&31)
        bf16x8 pf0, pf1, pf2, pf3;
        MKFRAG(pf0, wds0, 0)   // j  0..15
        MKFRAG(pf1, wds0, 1)   // j 16..31
        MKFRAG(pf2, wds1, 0)   // j 32..47
        MKFRAG(pf3, wds1, 1)   // j 48..63
        PVSTEP(pf0,  0)
        PVSTEP(pf1, 16)
        PVSTEP(pf2, 32)
        PVSTEP(pf3, 48)

        __syncthreads();
        if (kt + 1 < NT) STORE();
        __syncthreads();
    }

    // ---- write partials: O layout col d = lane&31(+32), row i=(r&3)+8*(r>>2)+4h
    size_t pb = ((size_t)half * 128 + bid) * 128;
    #pragma unroll
    for (int r = 0; r < 16; ++r){
        int iO = w * 32 + (r & 3) + 8 * (r >> 2) + 4 * hbit;
        OpU[(pb + iO) * 64 + l31]      = f2b(oacc0[r]);
        OpU[(pb + iO) * 64 + 32 + l31] = f2b(oacc1[r]);
    }
    if (hbit == 0){
        mpart[pb + i_loc] = mrow;
        lpart[pb + i_loc] = lacc;
    }
#undef MFMA32
#undef PACK8
#undef MKFRAG
#undef PVSTEP
}

// ---------------------------------------------------------------------------
// Combine 8 K-eighths -> normalized bf16 Oatt.
// ---------------------------------------------------------------------------
__global__ __launch_bounds__(256) void combine_kernel(const u16* __restrict__ OpU,
    const float* __restrict__ mpart, const float* __restrict__ lpart,
    u16* __restrict__ Oatt){
    int i0 = blockIdx.x * 128;
    int h  = blockIdx.y;
    int bid = blockIdx.x * NH + h;
    int t = threadIdx.x;
    int r = t >> 1, cb = (t & 1) * 32;
    size_t pr[8];
    float ms[8], ls[8];
    float m = -1e30f;
    #pragma unroll
    for (int s = 0; s < 8; ++s){
        pr[s] = ((size_t)s * 128 + bid) * 128 + r;
        ms[s] = mpart[pr[s]];
        ls[s] = lpart[pr[s]];
        m = fmaxf(m, ms[s]);
    }
    float den = 0.f, wgt[8];
    #pragma unroll
    for (int s = 0; s < 8; ++s){ wgt[s] = __expf(ms[s] - m); den += wgt[s] * ls[s]; }
    float inv = 1.0f / fmaxf(den, 1e-30f);
    float o[32];
    #pragma unroll
    for (int e = 0; e < 32; ++e) o[e] = 0.f;
    #pragma unroll
    for (int s = 0; s < 8; ++s){
        #pragma unroll
        for (int c = 0; c < 4; ++c){
            u16x8 a = *(const u16x8*)&OpU[pr[s] * 64 + cb + c * 8];
            #pragma unroll
            for (int e = 0; e < 8; ++e) o[c * 8 + e] += wgt[s] * b2f(a[e]);
        }
    }
    size_t ob = (size_t)(i0 + r) * HD + h * DK + cb;
    #pragma unroll
    for (int c = 0; c < 4; ++c){
        u16x8 rv;
        #pragma unroll
        for (int e = 0; e < 8; ++e) rv[e] = f2b(o[c * 8 + e] * inv);
        *(u16x8*)&Oatt[ob + c * 8] = rv;
    }
}

// ---------------------------------------------------------------------------
// Output projection: out = Oattn @ Wo + bo (fp32 W/bias/out). Unchanged.
// ---------------------------------------------------------------------------
__global__ __launch_bounds__(256) void oproj_kernel(const u16* __restrict__ A,
    const float* __restrict__ Wo, const float* __restrict__ bo,
    float* __restrict__ out, int m_base){
    __shared__ __align__(16) u16 xs[64 * 72];
    __shared__ __align__(16) u16 bs[64 * 72];
    int m0 = m_base + blockIdx.y * 64;
    int n0 = blockIdx.x * 64;
    int t = threadIdx.x;
    int w = t >> 6, lane = t & 63, qd = lane >> 4, l15 = lane & 15;
    f32x4 acc[4] = {{0,0,0,0},{0,0,0,0},{0,0,0,0},{0,0,0,0}};
    for (int k0 = 0; k0 < HD; k0 += 64){
        #pragma unroll
        for (int rep = 0; rep < 2; ++rep){
            int vid = rep * 256 + t;
            int r  = vid >> 3;
            int cv = (vid & 7) * 8;
            *(u16x8*)&xs[r * 72 + cv] = *(const u16x8*)&A[(size_t)(m0 + r) * HD + k0 + cv];
            size_t wi = (size_t)(k0 + r) * DIMM + n0 + cv;
            f32x4 wa = *(const f32x4*)(Wo + wi), wb = *(const f32x4*)(Wo + wi + 4);
            u16x8 wv;
            #pragma unroll
            for (int e = 0; e < 4; ++e){ wv[e] = f2b(wa[e]); wv[4 + e] = f2b(wb[e]); }
            #pragma unroll
            for (int e = 0; e < 8; ++e) bs[(cv + e) * 72 + r] = wv[e];
        }
        __syncthreads();
        bf16x8 a0 = ldfrag(&xs[(w * 16 + l15) * 72 +  0 + qd * 8]);
        bf16x8 a1 = ldfrag(&xs[(w * 16 + l15) * 72 + 32 + qd * 8]);
        #pragma unroll
        for (int nt = 0; nt < 4; ++nt){
            bf16x8 b0 = ldfrag(&bs[(nt * 16 + l15) * 72 +  0 + qd * 8]);
            bf16x8 b1 = ldfrag(&bs[(nt * 16 + l15) * 72 + 32 + qd * 8]);
            acc[nt] = __builtin_amdgcn_mfma_f32_16x16x32_bf16(a0, b0, acc[nt], 0, 0, 0);
            acc[nt] = __builtin_amdgcn_mfma_f32_16x16x32_bf16(a1, b1, acc[nt], 0, 0, 0);
        }
        __syncthreads();
    }
    #pragma unroll
    for (int nt = 0; nt < 4; ++nt)
        #pragma unroll
        for (int reg = 0; reg < 4; ++reg){
            int row = m0 + w * 16 + qd * 4 + reg;
            int col = n0 + nt * 16 + l15;
            out[(size_t)row * DIMM + col] = acc[nt][reg] + bo[col];
        }
}

extern "C" void kernel_launch(void* const* d_in, const int* in_sizes, int n_in,
                              void* d_out, int out_size, void* d_ws, size_t ws_size,
                              hipStream_t stream){
    const float* X  = (const float*)d_in[0];
    const float* Wq = (const float*)d_in[1];
    const float* Wk = (const float*)d_in[2];
    const float* Wv = (const float*)d_in[3];
    const float* Wr = (const float*)d_in[4];
    const float* Wo = (const float*)d_in[5];
    const float* bo = (const float*)d_in[6];
    const float* CB = (const float*)d_in[7];
    const float* PB = (const float*)d_in[8];
    float* out = (float*)d_out;
    u16* base = (u16*)d_out;   // 12,582,912 u16 slots

    // d_out scratch layout (u16 offsets):
    //   Qb   [0, 1048576)          (Oatt overlays this after attn)
    //   Kb   [1048576, 2097152)
    //   Vt   [2097152, 3145728)
    //   Wt   [3145728, 4325376)    dead after qkv; OpU overlays it:
    //   OpU  [3145728, 11534336)   8 splits x 128 bid x 128 rows x 64
    //   mpart f32 @ u16 [11534336, 11796480), lpart [11796480, 12058624)
    u16* Qb   = base;
    u16* Kb   = base + 1048576;
    u16* Vt   = base + 2097152;
    u16* Wt   = base + 3145728;
    u16* OpU  = base + 3145728;
    float* mpart = out + 5767168;
    float* lpart = out + 5898240;
    u16* Oatt = base;              // overlays Qb (dead after attn)

    unsigned char* fmtg = (unsigned char*)d_ws;
    u16* WsP = (u16*)((char*)d_ws + 4096);    // 4h x 32 x 64 bf16 = 16384 B
    u16* WsM = (u16*)((char*)d_ws + 20480);   // 16384 B

    convwt_kernel<<<dim3(576), 256, 0, stream>>>(Wq, Wk, Wv, Wt);
    fmtab_kernel<<<dim3(16), 256, 0, stream>>>(fmtg);
    wsuf_kernel<<<dim3(1), 256, 0, stream>>>(Wr, WsP, WsM);
    qkv_kernel<<<dim3(4, 64), 256, 0, stream>>>(X, Wt, Qb, Kb, Vt);
    attn_kernel<<<dim3(32, NH, KSPLIT), 256, 0, stream>>>(Qb, Kb, Vt, WsP, WsM,
                                                          fmtg, CB, PB,
                                                          OpU, mpart, lpart);
    combine_kernel<<<dim3(32, NH), 256, 0, stream>>>(OpU, mpart, lpart, Oatt);

    // oproj in DESCENDING row order so out-writes (u16-view 3072/row) never
    // clobber Oatt rows (256/row) still to be read:
    //   [384,4096): writes start at u16 1,179,648 > Oatt end 1,048,576 — safe.
    //   [64,384):   writes [196608,..) > its own read region [16384, 98304).
    //   [0,64):     single block; reads complete before epilogue writes.
    oproj_kernel<<<dim3(24, 58), 256, 0, stream>>>(Oatt, Wo, bo, out, 384);
    oproj_kernel<<<dim3(24,  5), 256, 0, stream>>>(Oatt, Wo, bo, out, 64);
    oproj_kernel<<<dim3(24,  1), 256, 0, stream>>>(Oatt, Wo, bo, out, 0);
}

// Round 2
// 233.716 us; speedup vs baseline: 1.2158x; 1.1870x over previous
//
#include <hip/hip_runtime.h>
#include <hip/hip_bf16.h>

#define N_SEQ 4096
#define DIMM  1536
#define NH    4
#define DK    64
#define HD    256     // NH*DK
#define QK_SCALE 0.125f
#define WSZ   393216  // 1536*256 per weight
#define KSPLIT 8

typedef __bf16 bf16x8 __attribute__((ext_vector_type(8)));
typedef unsigned short u16;
typedef u16   u16x8  __attribute__((ext_vector_type(8)));
typedef u16   u16x4  __attribute__((ext_vector_type(4)));
typedef float f32x4  __attribute__((ext_vector_type(4)));
typedef float f32x16 __attribute__((ext_vector_type(16)));
typedef unsigned int u32x4 __attribute__((ext_vector_type(4)));

__device__ inline float b2f(u16 u){
    union { float f; unsigned int i; } v; v.i = ((unsigned int)u) << 16; return v.f;
}
__device__ inline u16 f2b(float f){
    __bf16 h = (__bf16)f;               // native cvt, RNE
    return __builtin_bit_cast(u16, h);
}
__device__ inline bf16x8 ldfrag(const u16* p){
    return __builtin_bit_cast(bf16x8, *(const u16x8*)p);
}
__device__ inline f32x16 zero16(){
    f32x16 v;
    #pragma unroll
    for (int i = 0; i < 16; ++i) v[i] = 0.f;
    return v;
}
__device__ inline float pair_sum(unsigned int wd){
    union { unsigned int i; float f; } lo, hi;
    lo.i = wd << 16; hi.i = wd & 0xffff0000u;
    return lo.f + hi.f;
}

// ---------------------------------------------------------------------------
// Convert Wq|Wk|Wv (fp32, [k][n]) -> Wt (bf16, TRANSPOSED [n][k]).
// ---------------------------------------------------------------------------
__global__ __launch_bounds__(256) void convwt_kernel(const float* __restrict__ Wq,
    const float* __restrict__ Wk, const float* __restrict__ Wv, u16* __restrict__ Wt){
    int idx = (blockIdx.x * 256 + threadIdx.x) * 8;   // 576 blocks
    int s = idx / WSZ, off = idx % WSZ;
    int n = off / DIMM, k = off % DIMM;
    const float* W = (s == 0) ? Wq : (s == 1 ? Wk : Wv);
    u16x8 o;
    #pragma unroll
    for (int e = 0; e < 8; ++e) o[e] = f2b(W[(size_t)(k + e) * HD + n]);
    *(u16x8*)&Wt[idx] = o;
}

// ---------------------------------------------------------------------------
// fmtab[ad] = #{f in [0,32): cw[f] <= ad}
// ---------------------------------------------------------------------------
__global__ __launch_bounds__(256) void fmtab_kernel(unsigned char* __restrict__ fmt){
    int d = blockIdx.x * 256 + threadIdx.x;           // 16 blocks
    float lg = logf((float)(N_SEQ + 1)) * (1.0f / 32.0f);
    float ad = (float)d;
    int fm = 0;
    for (int f = 0; f < 32; ++f){
        float cw = expf(lg * (float)(f + 1)) - 1.0f;
        fm += (cw <= ad) ? 1 : 0;
    }
    fmt[d] = (unsigned char)fm;
}

// ---------------------------------------------------------------------------
// Suffix-summed relative-position weights (f32 accumulate, bf16 store).
// ---------------------------------------------------------------------------
__global__ __launch_bounds__(256) void wsuf_kernel(const float* __restrict__ Wrel,
    u16* __restrict__ WsP, u16* __restrict__ WsM){
    int t = threadIdx.x;                 // 1 block
    int h = t >> 6, d = t & 63;
    float a1 = 0.f, a2 = 0.f;
    for (int fm = 31; fm >= 0; --fm){
        a1 += Wrel[(size_t)fm * HD + h * DK + d];
        a2 += Wrel[(size_t)(32 + fm) * HD + h * DK + d];
        WsP[(h * 32 + fm) * 64 + d] = f2b(a1 + a2);
        WsM[(h * 32 + fm) * 64 + d] = f2b(a1 - a2);
    }
}

// ---------------------------------------------------------------------------
// QKV projection, v2: per-projection blocks (grid 12 x 64 = 768 blocks,
// 3 blocks/CU) + register-prefetch 2-phase pipeline (loads for tile k+1
// issued right after the barrier, hidden under MFMA of tile k).
// ---------------------------------------------------------------------------
__global__ __launch_bounds__(256) void qkv_kernel(const float* __restrict__ X,
    const u16* __restrict__ Wt,
    u16* __restrict__ Q, u16* __restrict__ K, u16* __restrict__ Vt){
    __shared__ __align__(16) u16 xs[64 * 72];
    __shared__ __align__(16) u16 bs[64 * 72];
    int s  = blockIdx.x >> 2;             // 0:Q 1:K 2:V
    int n0 = (blockIdx.x & 3) * 64;
    int m0 = blockIdx.y * 64;
    int t = threadIdx.x;
    int w = t >> 6, lane = t & 63, qd = lane >> 4, l15 = lane & 15;
    int r  = t >> 3;                      // staging row 0..31 (+32 on rep 1)
    int cv = (t & 7) * 8;                 // staging col
    f32x4 acc[4] = {{0,0,0,0},{0,0,0,0},{0,0,0,0},{0,0,0,0}};

    f32x4 xa[2], xb[2];
    u16x8 wv[2];
    auto LOAD = [&](int k0){
        #pragma unroll
        for (int rep = 0; rep < 2; ++rep){
            int rr = rep * 32 + r;
            size_t xi = (size_t)(m0 + rr) * DIMM + k0 + cv;
            xa[rep] = *(const f32x4*)(X + xi);
            xb[rep] = *(const f32x4*)(X + xi + 4);
            wv[rep] = *(const u16x8*)&Wt[(size_t)s * WSZ + (size_t)(n0 + rr) * DIMM + k0 + cv];
        }
    };
    auto STORE = [&](){
        #pragma unroll
        for (int rep = 0; rep < 2; ++rep){
            int rr = rep * 32 + r;
            u16x8 xv;
            #pragma unroll
            for (int e = 0; e < 4; ++e){ xv[e] = f2b(xa[rep][e]); xv[4 + e] = f2b(xb[rep][e]); }
            *(u16x8*)&xs[rr * 72 + cv] = xv;
            *(u16x8*)&bs[rr * 72 + cv] = wv[rep];
        }
    };

    LOAD(0);
    for (int k0 = 0; k0 < DIMM; k0 += 64){
        STORE();
        __syncthreads();
        if (k0 + 64 < DIMM) LOAD(k0 + 64);
        bf16x8 a0 = ldfrag(&xs[(w * 16 + l15) * 72 +  0 + qd * 8]);
        bf16x8 a1 = ldfrag(&xs[(w * 16 + l15) * 72 + 32 + qd * 8]);
        #pragma unroll
        for (int nt = 0; nt < 4; ++nt){
            bf16x8 b0 = ldfrag(&bs[(nt * 16 + l15) * 72 +  0 + qd * 8]);
            bf16x8 b1 = ldfrag(&bs[(nt * 16 + l15) * 72 + 32 + qd * 8]);
            acc[nt] = __builtin_amdgcn_mfma_f32_16x16x32_bf16(a0, b0, acc[nt], 0, 0, 0);
            acc[nt] = __builtin_amdgcn_mfma_f32_16x16x32_bf16(a1, b1, acc[nt], 0, 0, 0);
        }
        __syncthreads();
    }

    int row0 = m0 + w * 16 + qd * 4;
    if (s == 0){
        #pragma unroll
        for (int nt = 0; nt < 4; ++nt){
            int col = n0 + nt * 16 + l15;
            #pragma unroll
            for (int reg = 0; reg < 4; ++reg)
                Q[(size_t)(row0 + reg) * HD + col] = f2b(acc[nt][reg] * QK_SCALE);
        }
    } else if (s == 1){
        #pragma unroll
        for (int nt = 0; nt < 4; ++nt){
            int col = n0 + nt * 16 + l15;
            #pragma unroll
            for (int reg = 0; reg < 4; ++reg)
                K[(size_t)(row0 + reg) * HD + col] = f2b(acc[nt][reg]);
        }
    } else {
        #pragma unroll
        for (int nt = 0; nt < 4; ++nt){
            int col = n0 + nt * 16 + l15;
            u16x4 pv;
            #pragma unroll
            for (int reg = 0; reg < 4; ++reg) pv[reg] = f2b(acc[nt][reg]);
            *(u16x4*)&Vt[(size_t)col * N_SEQ + row0] = pv;
        }
    }
}

// ---------------------------------------------------------------------------
// Flash attention (unchanged from round 1): 32x32x16 MFMA, swapped QK^T,
// in-register P transpose, MFMA-built rel tables, defer-max online softmax.
// ---------------------------------------------------------------------------
__global__ __launch_bounds__(256) void attn_kernel(const u16* __restrict__ Q,
    const u16* __restrict__ Kg, const u16* __restrict__ Vt,
    const u16* __restrict__ WsPg, const u16* __restrict__ WsMg,
    const unsigned char* __restrict__ fmtg,
    const float* __restrict__ CB, const float* __restrict__ PB,
    u16* __restrict__ OpU, float* __restrict__ mpart, float* __restrict__ lpart){
    __shared__ __align__(16) unsigned char smem[39936];
    u16* Ks   = (u16*)(smem);             // [64][72]  main loop
    u16* Vts  = (u16*)(smem + 9216);      // [64][72]  main loop
    u16* Qs   = (u16*)(smem);             // init alias: [128][72]
    u16* relP = (u16*)(smem + 18432);     // [128][34] u16
    u16* relM = (u16*)(smem + 27136);     // [128][34] u16
    unsigned char* fmt = smem + 35840;    // 4096
    u16* WsPs = (u16*)(smem + 18432);     // init alias: [32][72]
    u16* WsMs = (u16*)(smem + 23040);     // init alias: [32][72]

    int i0   = blockIdx.x * 128;
    int h    = blockIdx.y;
    int half = blockIdx.z;                // 0..7
    int bid  = blockIdx.x * NH + h;       // 0..127
    int jbase = half * (N_SEQ / KSPLIT);
    const int NT = (N_SEQ / KSPLIT) / 64; // 8 tiles
    int t = threadIdx.x;
    int w = t >> 6, lane = t & 63, l31 = lane & 31, hbit = lane >> 5;
    int h8 = hbit * 8;
    int i_loc = w * 32 + l31;             // this lane's softmax row (block-local)

    int sr = t >> 3, scv = (t & 7) * 8;
    u16x8 kr0, kr1, vr0, vr1;
    auto LOAD = [&](int j0){
        kr0 = *(const u16x8*)&Kg[(size_t)(j0 + sr)      * HD + h * DK + scv];
        kr1 = *(const u16x8*)&Kg[(size_t)(j0 + 32 + sr) * HD + h * DK + scv];
        vr0 = *(const u16x8*)&Vt[(size_t)(h * 64 + sr)      * N_SEQ + j0 + scv];
        vr1 = *(const u16x8*)&Vt[(size_t)(h * 64 + 32 + sr) * N_SEQ + j0 + scv];
    };
    auto STORE = [&](){
        *(u16x8*)&Ks [(sr)      * 72 + scv] = kr0;
        *(u16x8*)&Ks [(32 + sr) * 72 + scv] = kr1;
        *(u16x8*)&Vts[(sr)      * 72 + scv] = vr0;
        *(u16x8*)&Vts[(32 + sr) * 72 + scv] = vr1;
    };
    LOAD(jbase);

    // ---- init staging: Q rows (raw bf16), Wsuf slices, fmt ----
    #pragma unroll
    for (int rep = 0; rep < 4; ++rep){
        int vid = rep * 256 + t;
        int r  = vid >> 3;
        int cv = (vid & 7) * 8;
        *(u16x8*)&Qs[r * 72 + cv] = *(const u16x8*)&Q[(size_t)(i0 + r) * HD + h * DK + cv];
    }
    {
        int r = t >> 3, cv = (t & 7) * 8;
        *(u16x8*)&WsPs[r * 72 + cv] = *(const u16x8*)&WsPg[(h * 32 + r) * 64 + cv];
        *(u16x8*)&WsMs[r * 72 + cv] = *(const u16x8*)&WsMg[(h * 32 + r) * 64 + cv];
    }
    ((uint4*)fmt)[t] = ((const uint4*)fmtg)[t];
    __syncthreads();

    // ---- per-lane Q fragments (B-operand layout), bias folded in ----
    bf16x8 qcF[4], qpF[4];
    #pragma unroll
    for (int kc = 0; kc < 4; ++kc){
        bf16x8 raw = ldfrag(&Qs[i_loc * 72 + kc * 16 + h8]);
        const float* cbp = CB + h * DK + kc * 16 + h8;
        const float* pbp = PB + h * DK + kc * 16 + h8;
        bf16x8 qc, qp;
        #pragma unroll
        for (int e = 0; e < 8; ++e){
            float qf = (float)raw[e];
            qc[e] = (__bf16)(qf + cbp[e]);
            qp[e] = (__bf16)(qf + pbp[e]);
        }
        qcF[kc] = qc; qpF[kc] = qp;
    }

    // ---- rel tables via MFMA: C[fm][i] = Wsuf[fm] . qp[i] ----
    f32x16 rP = zero16(), rM = zero16();
    #pragma unroll
    for (int kc = 0; kc < 4; ++kc){
        bf16x8 aP = ldfrag(&WsPs[l31 * 72 + kc * 16 + h8]);
        bf16x8 aM = ldfrag(&WsMs[l31 * 72 + kc * 16 + h8]);
        rP = __builtin_amdgcn_mfma_f32_32x32x16_bf16(aP, qpF[kc], rP, 0, 0, 0);
        rM = __builtin_amdgcn_mfma_f32_32x32x16_bf16(aM, qpF[kc], rM, 0, 0, 0);
    }
    __syncthreads();   // all LDS reads (Qs, Wsuf) done before overwrites

    #pragma unroll
    for (int r = 0; r < 16; ++r){
        int fm = (r & 3) + 8 * (r >> 2) + 4 * hbit;
        relP[i_loc * 34 + fm] = f2b(rP[r]);
        relM[i_loc * 34 + fm] = f2b(rM[r]);
    }
    if (hbit == 0){
        relP[i_loc * 34 + 33] = f2b((rP[0] + rM[0]) * 0.5f);  // d==0: s1 = (P0+M0)/2
        relP[i_loc * 34 + 32] = 0;                            // fm==32: no features
        relM[i_loc * 34 + 32] = 0;
        relM[i_loc * 34 + 33] = 0;
    }
    STORE();           // K/V tile 0 into seg0 (Qs dead)
    __syncthreads();

    // ---- main K-loop ----
    float mrow = -1e30f, lacc = 0.f;
    f32x16 oacc0 = zero16(), oacc1 = zero16();

#define MFMA32(A, B, C) __builtin_amdgcn_mfma_f32_32x32x16_bf16(A, B, C, 0, 0, 0)

#define PACK8(ST, WD) { \
    _Pragma("unroll") \
    for (int q_ = 0; q_ < 8; ++q_){ \
        float pa_ = __expf(ST[2 * q_]     - mrow); \
        float pc_ = __expf(ST[2 * q_ + 1] - mrow); \
        unsigned int wd_ = (unsigned int)f2b(pa_) | ((unsigned int)f2b(pc_) << 16); \
        WD[q_] = wd_; \
        lsum += pair_sum(wd_); \
    } }

#define MKFRAG(DST, WD, ZZ) { \
    unsigned int a0_ = WD[(ZZ) * 4 + 0], a1_ = WD[(ZZ) * 4 + 1]; \
    unsigned int b0_ = WD[(ZZ) * 4 + 2], b1_ = WD[(ZZ) * 4 + 3]; \
    unsigned int xa0_ = (unsigned int)__shfl_xor((int)a0_, 32); \
    unsigned int xa1_ = (unsigned int)__shfl_xor((int)a1_, 32); \
    unsigned int xb0_ = (unsigned int)__shfl_xor((int)b0_, 32); \
    unsigned int xb1_ = (unsigned int)__shfl_xor((int)b1_, 32); \
    u32x4 fw_; \
    fw_[0] = hbit ? xb0_ : a0_; \
    fw_[1] = hbit ? xb1_ : a1_; \
    fw_[2] = hbit ? b0_  : xa0_; \
    fw_[3] = hbit ? b1_  : xa1_; \
    DST = __builtin_bit_cast(bf16x8, fw_); }

#define PVSTEP(PF, COL) { \
    oacc0 = MFMA32(PF, ldfrag(&Vts[(l31)      * 72 + (COL) + h8]), oacc0); \
    oacc1 = MFMA32(PF, ldfrag(&Vts[(32 + l31) * 72 + (COL) + h8]), oacc1); }

    for (int kt = 0; kt < NT; ++kt){
        int j0 = jbase + kt * 64;
        if (kt + 1 < NT) LOAD(j0 + 64);

        // S^T = K . Q^T : st0 = rows j 0..31, st1 = rows j 32..63; col i = lane&31
        f32x16 st0 = zero16(), st1 = zero16();
        #pragma unroll
        for (int kc = 0; kc < 4; ++kc){
            bf16x8 k0 = ldfrag(&Ks[(l31)      * 72 + kc * 16 + h8]);
            bf16x8 k1 = ldfrag(&Ks[(32 + l31) * 72 + kc * 16 + h8]);
            st0 = MFMA32(k0, qcF[kc], st0);
            st1 = MFMA32(k1, qcF[kc], st1);
        }

        // rel merge; lane row i fixed -> fast path is ONE table read per lane
        int D = j0 - i0;
        bool fast = false; int fmU = 0; const u16* tabU = relP;
        if (D >= 128){
            int fa = fmt[D - 127], fb = fmt[D + 63];
            fast = (fa == fb); fmU = fa; tabU = relP;
        } else if (D <= -64){
            int fa = fmt[-D - 63], fb = fmt[-D + 127];
            fast = (fa == fb); fmU = fa; tabU = relM;
        }
        if (fast){
            float relv = b2f(tabU[i_loc * 34 + fmU]);
            #pragma unroll
            for (int r = 0; r < 16; ++r){ st0[r] += relv; st1[r] += relv; }
        } else {
            #pragma unroll
            for (int r = 0; r < 16; ++r){
                int jb = (r & 3) + 8 * (r >> 2) + 4 * hbit;
                {
                    int dd = D + jb - i_loc;
                    int ad = dd < 0 ? -dd : dd;
                    int fm = fmt[ad];
                    const u16* tab = (dd >= 0) ? relP : relM;
                    st0[r] += b2f(tab[i_loc * 34 + ((dd == 0) ? 33 : fm)]);
                }
                {
                    int dd = D + 32 + jb - i_loc;
                    int ad = dd < 0 ? -dd : dd;
                    int fm = fmt[ad];
                    const u16* tab = (dd >= 0) ? relP : relM;
                    st1[r] += b2f(tab[i_loc * 34 + ((dd == 0) ? 33 : fm)]);
                }
            }
        }

        // row max (lane-local + one cross-half shuffle)
        float mx = st0[0];
        #pragma unroll
        for (int r = 1; r < 16; ++r) mx = fmaxf(mx, st0[r]);
        #pragma unroll
        for (int r = 0; r < 16; ++r) mx = fmaxf(mx, st1[r]);
        mx = fmaxf(mx, __shfl_xor(mx, 32));

        // defer-max: rescale only when the bound would be exceeded (THR=8)
        if (!__all(mx - mrow <= 8.0f)){
            float mnew = fmaxf(mrow, mx);
            float alpha = __expf(mrow - mnew);
            mrow = mnew;
            lacc *= alpha;
            #pragma unroll
            for (int r = 0; r < 16; ++r){
                float ar = __shfl(alpha, (r & 3) + 8 * (r >> 2) + 4 * hbit);
                oacc0[r] *= ar; oacc1[r] *= ar;
            }
        }

        // P = exp(S - mrow), packed to bf16 words; l from rounded values
        float lsum = 0.f;
        unsigned int wds0[8], wds1[8];
        PACK8(st0, wds0)
        PACK8(st1, wds1)
        lacc += lsum + __shfl_xor(lsum, 32);

        // in-register transpose to PV A-fragments (rows i = lane&31)
        bf16x8 pf0, pf1, pf2, pf3;
        MKFRAG(pf0, wds0, 0)   // j  0..15
        MKFRAG(pf1, wds0, 1)   // j 16..31
        MKFRAG(pf2, wds1, 0)   // j 32..47
        MKFRAG(pf3, wds1, 1)   // j 48..63
        PVSTEP(pf0,  0)
        PVSTEP(pf1, 16)
        PVSTEP(pf2, 32)
        PVSTEP(pf3, 48)

        __syncthreads();
        if (kt + 1 < NT) STORE();
        __syncthreads();
    }

    // ---- write partials ----
    size_t pb = ((size_t)half * 128 + bid) * 128;
    #pragma unroll
    for (int r = 0; r < 16; ++r){
        int iO = w * 32 + (r & 3) + 8 * (r >> 2) + 4 * hbit;
        OpU[(pb + iO) * 64 + l31]      = f2b(oacc0[r]);
        OpU[(pb + iO) * 64 + 32 + l31] = f2b(oacc1[r]);
    }
    if (hbit == 0){
        mpart[pb + i_loc] = mrow;
        lpart[pb + i_loc] = lacc;
    }
#undef MFMA32
#undef PACK8
#undef MKFRAG
#undef PVSTEP
}

// ---------------------------------------------------------------------------
// Combine 8 K-eighths -> normalized bf16 Oatt.
// ---------------------------------------------------------------------------
__global__ __launch_bounds__(256) void combine_kernel(const u16* __restrict__ OpU,
    const float* __restrict__ mpart, const float* __restrict__ lpart,
    u16* __restrict__ Oatt){
    int i0 = blockIdx.x * 128;
    int h  = blockIdx.y;
    int bid = blockIdx.x * NH + h;
    int t = threadIdx.x;
    int r = t >> 1, cb = (t & 1) * 32;
    size_t pr[8];
    float ms[8], ls[8];
    float m = -1e30f;
    #pragma unroll
    for (int s = 0; s < 8; ++s){
        pr[s] = ((size_t)s * 128 + bid) * 128 + r;
        ms[s] = mpart[pr[s]];
        ls[s] = lpart[pr[s]];
        m = fmaxf(m, ms[s]);
    }
    float den = 0.f, wgt[8];
    #pragma unroll
    for (int s = 0; s < 8; ++s){ wgt[s] = __expf(ms[s] - m); den += wgt[s] * ls[s]; }
    float inv = 1.0f / fmaxf(den, 1e-30f);
    float o[32];
    #pragma unroll
    for (int e = 0; e < 32; ++e) o[e] = 0.f;
    #pragma unroll
    for (int s = 0; s < 8; ++s){
        #pragma unroll
        for (int c = 0; c < 4; ++c){
            u16x8 a = *(const u16x8*)&OpU[pr[s] * 64 + cb + c * 8];
            #pragma unroll
            for (int e = 0; e < 8; ++e) o[c * 8 + e] += wgt[s] * b2f(a[e]);
        }
    }
    size_t ob = (size_t)(i0 + r) * HD + h * DK + cb;
    #pragma unroll
    for (int c = 0; c < 4; ++c){
        u16x8 rv;
        #pragma unroll
        for (int e = 0; e < 8; ++e) rv[e] = f2b(o[c * 8 + e] * inv);
        *(u16x8*)&Oatt[ob + c * 8] = rv;
    }
}

// ---------------------------------------------------------------------------
// Output projection: out = Oattn @ Wo + bo (fp32 W/bias/out). Unchanged.
// ---------------------------------------------------------------------------
__global__ __launch_bounds__(256) void oproj_kernel(const u16* __restrict__ A,
    const float* __restrict__ Wo, const float* __restrict__ bo,
    float* __restrict__ out, int m_base){
    __shared__ __align__(16) u16 xs[64 * 72];
    __shared__ __align__(16) u16 bs[64 * 72];
    int m0 = m_base + blockIdx.y * 64;
    int n0 = blockIdx.x * 64;
    int t = threadIdx.x;
    int w = t >> 6, lane = t & 63, qd = lane >> 4, l15 = lane & 15;
    f32x4 acc[4] = {{0,0,0,0},{0,0,0,0},{0,0,0,0},{0,0,0,0}};
    for (int k0 = 0; k0 < HD; k0 += 64){
        #pragma unroll
        for (int rep = 0; rep < 2; ++rep){
            int vid = rep * 256 + t;
            int r  = vid >> 3;
            int cv = (vid & 7) * 8;
            *(u16x8*)&xs[r * 72 + cv] = *(const u16x8*)&A[(size_t)(m0 + r) * HD + k0 + cv];
            size_t wi = (size_t)(k0 + r) * DIMM + n0 + cv;
            f32x4 wa = *(const f32x4*)(Wo + wi), wb = *(const f32x4*)(Wo + wi + 4);
            u16x8 wv;
            #pragma unroll
            for (int e = 0; e < 4; ++e){ wv[e] = f2b(wa[e]); wv[4 + e] = f2b(wb[e]); }
            #pragma unroll
            for (int e = 0; e < 8; ++e) bs[(cv + e) * 72 + r] = wv[e];
        }
        __syncthreads();
        bf16x8 a0 = ldfrag(&xs[(w * 16 + l15) * 72 +  0 + qd * 8]);
        bf16x8 a1 = ldfrag(&xs[(w * 16 + l15) * 72 + 32 + qd * 8]);
        #pragma unroll
        for (int nt = 0; nt < 4; ++nt){
            bf16x8 b0 = ldfrag(&bs[(nt * 16 + l15) * 72 +  0 + qd * 8]);
            bf16x8 b1 = ldfrag(&bs[(nt * 16 + l15) * 72 + 32 + qd * 8]);
            acc[nt] = __builtin_amdgcn_mfma_f32_16x16x32_bf16(a0, b0, acc[nt], 0, 0, 0);
            acc[nt] = __builtin_amdgcn_mfma_f32_16x16x32_bf16(a1, b1, acc[nt], 0, 0, 0);
        }
        __syncthreads();
    }
    #pragma unroll
    for (int nt = 0; nt < 4; ++nt)
        #pragma unroll
        for (int reg = 0; reg < 4; ++reg){
            int row = m0 + w * 16 + qd * 4 + reg;
            int col = n0 + nt * 16 + l15;
            out[(size_t)row * DIMM + col] = acc[nt][reg] + bo[col];
        }
}

extern "C" void kernel_launch(void* const* d_in, const int* in_sizes, int n_in,
                              void* d_out, int out_size, void* d_ws, size_t ws_size,
                              hipStream_t stream){
    const float* X  = (const float*)d_in[0];
    const float* Wq = (const float*)d_in[1];
    const float* Wk = (const float*)d_in[2];
    const float* Wv = (const float*)d_in[3];
    const float* Wr = (const float*)d_in[4];
    const float* Wo = (const float*)d_in[5];
    const float* bo = (const float*)d_in[6];
    const float* CB = (const float*)d_in[7];
    const float* PB = (const float*)d_in[8];
    float* out = (float*)d_out;
    u16* base = (u16*)d_out;   // 12,582,912 u16 slots

    // d_out scratch layout (u16 offsets):
    //   Qb   [0, 1048576)          (Oatt overlays this after attn)
    //   Kb   [1048576, 2097152)
    //   Vt   [2097152, 3145728)
    //   Wt   [3145728, 4325376)    dead after qkv; OpU overlays it:
    //   OpU  [3145728, 11534336)   8 splits x 128 bid x 128 rows x 64
    //   mpart f32 @ u16 [11534336, 11796480), lpart [11796480, 12058624)
    u16* Qb   = base;
    u16* Kb   = base + 1048576;
    u16* Vt   = base + 2097152;
    u16* Wt   = base + 3145728;
    u16* OpU  = base + 3145728;
    float* mpart = out + 5767168;
    float* lpart = out + 5898240;
    u16* Oatt = base;              // overlays Qb (dead after attn)

    unsigned char* fmtg = (unsigned char*)d_ws;
    u16* WsP = (u16*)((char*)d_ws + 4096);    // 4h x 32 x 64 bf16 = 16384 B
    u16* WsM = (u16*)((char*)d_ws + 20480);   // 16384 B

    convwt_kernel<<<dim3(576), 256, 0, stream>>>(Wq, Wk, Wv, Wt);
    fmtab_kernel<<<dim3(16), 256, 0, stream>>>(fmtg);
    wsuf_kernel<<<dim3(1), 256, 0, stream>>>(Wr, WsP, WsM);
    qkv_kernel<<<dim3(12, 64), 256, 0, stream>>>(X, Wt, Qb, Kb, Vt);
    attn_kernel<<<dim3(32, NH, KSPLIT), 256, 0, stream>>>(Qb, Kb, Vt, WsP, WsM,
                                                          fmtg, CB, PB,
                                                          OpU, mpart, lpart);
    combine_kernel<<<dim3(32, NH), 256, 0, stream>>>(OpU, mpart, lpart, Oatt);

    // oproj in DESCENDING row order so out-writes (u16-view 3072/row) never
    // clobber Oatt rows (256/row) still to be read:
    //   [384,4096): writes start at u16 1,179,648 > Oatt end 1,048,576 — safe.
    //   [64,384):   writes [196608,..) > its own read region [16384, 98304).
    //   [0,64):     single block; reads complete before epilogue writes.
    oproj_kernel<<<dim3(24, 58), 256, 0, stream>>>(Oatt, Wo, bo, out, 384);
    oproj_kernel<<<dim3(24,  5), 256, 0, stream>>>(Oatt, Wo, bo, out, 64);
    oproj_kernel<<<dim3(24,  1), 256, 0, stream>>>(Oatt, Wo, bo, out, 0);
}

// Round 4
// 229.618 us; speedup vs baseline: 1.2375x; 1.0178x over previous
//
#include <hip/hip_runtime.h>
#include <hip/hip_bf16.h>

#define N_SEQ 4096
#define DIMM  1536
#define NH    4
#define DK    64
#define HD    256     // NH*DK
#define QK_SCALE 0.125f
#define WSZ   393216  // 1536*256 per weight
#define KSPLIT 8
#define LOG2E 1.44269504f

typedef __bf16 bf16x8 __attribute__((ext_vector_type(8)));
typedef unsigned short u16;
typedef u16   u16x8  __attribute__((ext_vector_type(8)));
typedef u16   u16x4  __attribute__((ext_vector_type(4)));
typedef float f32x4  __attribute__((ext_vector_type(4)));
typedef float f32x16 __attribute__((ext_vector_type(16)));
typedef unsigned int u32x4 __attribute__((ext_vector_type(4)));

__device__ inline float b2f(u16 u){
    union { float f; unsigned int i; } v; v.i = ((unsigned int)u) << 16; return v.f;
}
__device__ inline u16 f2b(float f){
    __bf16 h = (__bf16)f;               // native cvt, RNE
    return __builtin_bit_cast(u16, h);
}
__device__ inline bf16x8 ldfrag(const u16* p){
    return __builtin_bit_cast(bf16x8, *(const u16x8*)p);
}
__device__ inline f32x16 zero16(){
    f32x16 v;
    #pragma unroll
    for (int i = 0; i < 16; ++i) v[i] = 0.f;
    return v;
}
#define EXP2(x) exp2f(x)   // lowers to a single v_exp_f32 on gfx950

// ---------------------------------------------------------------------------
// Convert Wq|Wk|Wv (fp32, [k][n]) -> Wt (bf16, TRANSPOSED [n][k]).
// ---------------------------------------------------------------------------
__global__ __launch_bounds__(256) void convwt_kernel(const float* __restrict__ Wq,
    const float* __restrict__ Wk, const float* __restrict__ Wv, u16* __restrict__ Wt){
    int idx = (blockIdx.x * 256 + threadIdx.x) * 8;   // 576 blocks
    int s = idx / WSZ, off = idx % WSZ;
    int n = off / DIMM, k = off % DIMM;
    const float* W = (s == 0) ? Wq : (s == 1 ? Wk : Wv);
    u16x8 o;
    #pragma unroll
    for (int e = 0; e < 8; ++e) o[e] = f2b(W[(size_t)(k + e) * HD + n]);
    *(u16x8*)&Wt[idx] = o;
}

// ---------------------------------------------------------------------------
// fmtab[ad] = #{f in [0,32): cw[f] <= ad}; block 16 does the suffix-summed
// rel-position weights (wsuf) instead.
// ---------------------------------------------------------------------------
__global__ __launch_bounds__(256) void fmtab_kernel(unsigned char* __restrict__ fmt,
    const float* __restrict__ Wrel, u16* __restrict__ WsP, u16* __restrict__ WsM){
    int t = threadIdx.x;
    if (blockIdx.x == 16){
        // suffix-summed rel weights (f32 accumulate, bf16 store)
        int h = t >> 6, d = t & 63;
        float a1 = 0.f, a2 = 0.f;
        for (int fm = 31; fm >= 0; --fm){
            a1 += Wrel[(size_t)fm * HD + h * DK + d];
            a2 += Wrel[(size_t)(32 + fm) * HD + h * DK + d];
            WsP[(h * 32 + fm) * 64 + d] = f2b(a1 + a2);
            WsM[(h * 32 + fm) * 64 + d] = f2b(a1 - a2);
        }
        return;
    }
    int d = blockIdx.x * 256 + t;                     // 16 blocks
    float lg = logf((float)(N_SEQ + 1)) * (1.0f / 32.0f);
    float ad = (float)d;
    int fm = 0;
    for (int f = 0; f < 32; ++f){
        float cw = expf(lg * (float)(f + 1)) - 1.0f;
        fm += (cw <= ad) ? 1 : 0;
    }
    fmt[d] = (unsigned char)fm;
}

// ---------------------------------------------------------------------------
// QKV projection: per-projection blocks (grid 12 x 64 = 768 blocks) +
// register-prefetch 2-phase pipeline.
// ---------------------------------------------------------------------------
__global__ __launch_bounds__(256) void qkv_kernel(const float* __restrict__ X,
    const u16* __restrict__ Wt,
    u16* __restrict__ Q, u16* __restrict__ K, u16* __restrict__ Vt){
    __shared__ __align__(16) u16 xs[64 * 72];
    __shared__ __align__(16) u16 bs[64 * 72];
    int s  = blockIdx.x >> 2;             // 0:Q 1:K 2:V
    int n0 = (blockIdx.x & 3) * 64;
    int m0 = blockIdx.y * 64;
    int t = threadIdx.x;
    int w = t >> 6, lane = t & 63, qd = lane >> 4, l15 = lane & 15;
    int r  = t >> 3;                      // staging row 0..31 (+32 on rep 1)
    int cv = (t & 7) * 8;                 // staging col
    f32x4 acc[4] = {{0,0,0,0},{0,0,0,0},{0,0,0,0},{0,0,0,0}};

    f32x4 xa[2], xb[2];
    u16x8 wv[2];
    auto LOAD = [&](int k0){
        #pragma unroll
        for (int rep = 0; rep < 2; ++rep){
            int rr = rep * 32 + r;
            size_t xi = (size_t)(m0 + rr) * DIMM + k0 + cv;
            xa[rep] = *(const f32x4*)(X + xi);
            xb[rep] = *(const f32x4*)(X + xi + 4);
            wv[rep] = *(const u16x8*)&Wt[(size_t)s * WSZ + (size_t)(n0 + rr) * DIMM + k0 + cv];
        }
    };
    auto STORE = [&](){
        #pragma unroll
        for (int rep = 0; rep < 2; ++rep){
            int rr = rep * 32 + r;
            u16x8 xv;
            #pragma unroll
            for (int e = 0; e < 4; ++e){ xv[e] = f2b(xa[rep][e]); xv[4 + e] = f2b(xb[rep][e]); }
            *(u16x8*)&xs[rr * 72 + cv] = xv;
            *(u16x8*)&bs[rr * 72 + cv] = wv[rep];
        }
    };

    LOAD(0);
    for (int k0 = 0; k0 < DIMM; k0 += 64){
        STORE();
        __syncthreads();
        if (k0 + 64 < DIMM) LOAD(k0 + 64);
        bf16x8 a0 = ldfrag(&xs[(w * 16 + l15) * 72 +  0 + qd * 8]);
        bf16x8 a1 = ldfrag(&xs[(w * 16 + l15) * 72 + 32 + qd * 8]);
        #pragma unroll
        for (int nt = 0; nt < 4; ++nt){
            bf16x8 b0 = ldfrag(&bs[(nt * 16 + l15) * 72 +  0 + qd * 8]);
            bf16x8 b1 = ldfrag(&bs[(nt * 16 + l15) * 72 + 32 + qd * 8]);
            acc[nt] = __builtin_amdgcn_mfma_f32_16x16x32_bf16(a0, b0, acc[nt], 0, 0, 0);
            acc[nt] = __builtin_amdgcn_mfma_f32_16x16x32_bf16(a1, b1, acc[nt], 0, 0, 0);
        }
        __syncthreads();
    }

    int row0 = m0 + w * 16 + qd * 4;
    if (s == 0){
        #pragma unroll
        for (int nt = 0; nt < 4; ++nt){
            int col = n0 + nt * 16 + l15;
            #pragma unroll
            for (int reg = 0; reg < 4; ++reg)
                Q[(size_t)(row0 + reg) * HD + col] = f2b(acc[nt][reg] * QK_SCALE);
        }
    } else if (s == 1){
        #pragma unroll
        for (int nt = 0; nt < 4; ++nt){
            int col = n0 + nt * 16 + l15;
            #pragma unroll
            for (int reg = 0; reg < 4; ++reg)
                K[(size_t)(row0 + reg) * HD + col] = f2b(acc[nt][reg]);
        }
    } else {
        #pragma unroll
        for (int nt = 0; nt < 4; ++nt){
            int col = n0 + nt * 16 + l15;
            u16x4 pv;
            #pragma unroll
            for (int reg = 0; reg < 4; ++reg) pv[reg] = f2b(acc[nt][reg]);
            *(u16x4*)&Vt[(size_t)col * N_SEQ + row0] = pv;
        }
    }
}

// ---------------------------------------------------------------------------
// Flash attention: 32x32x16 MFMA, swapped QK^T, in-register P transpose,
// MFMA-built rel tables; exp2 domain, rel-into-bias fast path, slot-0 d==0
// trick, halved MKFRAG shuffles, float lsum, setprio around MFMA clusters.
// ---------------------------------------------------------------------------
__global__ __launch_bounds__(256) void attn_kernel(const u16* __restrict__ Q,
    const u16* __restrict__ Kg, const u16* __restrict__ Vt,
    const u16* __restrict__ WsPg, const u16* __restrict__ WsMg,
    const unsigned char* __restrict__ fmtg,
    const float* __restrict__ CB, const float* __restrict__ PB,
    u16* __restrict__ OpU, float* __restrict__ mpart, float* __restrict__ lpart){
    __shared__ __align__(16) unsigned char smem[39936];
    u16* Ks   = (u16*)(smem);             // [64][72]  main loop
    u16* Vts  = (u16*)(smem + 9216);      // [64][72]  main loop
    u16* Qs   = (u16*)(smem);             // init alias: [128][72]
    u16* relP = (u16*)(smem + 18432);     // [128][34] u16 (slot 0 = d==0 value)
    u16* relM = (u16*)(smem + 27136);     // [128][34] u16
    unsigned char* fmt = smem + 35840;    // 4096
    u16* WsPs = (u16*)(smem + 18432);     // init alias: [32][72]
    u16* WsMs = (u16*)(smem + 23040);     // init alias: [32][72]

    int i0   = blockIdx.x * 128;
    int h    = blockIdx.y;
    int half = blockIdx.z;                // 0..7
    int bid  = blockIdx.x * NH + h;       // 0..127
    int jbase = half * (N_SEQ / KSPLIT);
    const int NT = (N_SEQ / KSPLIT) / 64; // 8 tiles
    int t = threadIdx.x;
    int w = t >> 6, lane = t & 63, l31 = lane & 31, hbit = lane >> 5;
    int h8 = hbit * 8;
    int i_loc = w * 32 + l31;             // this lane's softmax row (block-local)

    int sr = t >> 3, scv = (t & 7) * 8;
    u16x8 kr0, kr1, vr0, vr1;
    auto LOAD = [&](int j0){
        kr0 = *(const u16x8*)&Kg[(size_t)(j0 + sr)      * HD + h * DK + scv];
        kr1 = *(const u16x8*)&Kg[(size_t)(j0 + 32 + sr) * HD + h * DK + scv];
        vr0 = *(const u16x8*)&Vt[(size_t)(h * 64 + sr)      * N_SEQ + j0 + scv];
        vr1 = *(const u16x8*)&Vt[(size_t)(h * 64 + 32 + sr) * N_SEQ + j0 + scv];
    };
    auto STORE = [&](){
        *(u16x8*)&Ks [(sr)      * 72 + scv] = kr0;
        *(u16x8*)&Ks [(32 + sr) * 72 + scv] = kr1;
        *(u16x8*)&Vts[(sr)      * 72 + scv] = vr0;
        *(u16x8*)&Vts[(32 + sr) * 72 + scv] = vr1;
    };
    LOAD(jbase);

    // ---- init staging: Q rows (raw bf16), Wsuf slices, fmt ----
    #pragma unroll
    for (int rep = 0; rep < 4; ++rep){
        int vid = rep * 256 + t;
        int r  = vid >> 3;
        int cv = (vid & 7) * 8;
        *(u16x8*)&Qs[r * 72 + cv] = *(const u16x8*)&Q[(size_t)(i0 + r) * HD + h * DK + cv];
    }
    {
        int r = t >> 3, cv = (t & 7) * 8;
        *(u16x8*)&WsPs[r * 72 + cv] = *(const u16x8*)&WsPg[(h * 32 + r) * 64 + cv];
        *(u16x8*)&WsMs[r * 72 + cv] = *(const u16x8*)&WsMg[(h * 32 + r) * 64 + cv];
    }
    ((uint4*)fmt)[t] = ((const uint4*)fmtg)[t];
    __syncthreads();

    // ---- per-lane Q fragments (B-operand layout), bias + LOG2E folded ----
    bf16x8 qcF[4], qpF[4];
    #pragma unroll
    for (int kc = 0; kc < 4; ++kc){
        bf16x8 raw = ldfrag(&Qs[i_loc * 72 + kc * 16 + h8]);
        const float* cbp = CB + h * DK + kc * 16 + h8;
        const float* pbp = PB + h * DK + kc * 16 + h8;
        bf16x8 qc, qp;
        #pragma unroll
        for (int e = 0; e < 8; ++e){
            float qf = (float)raw[e];
            qc[e] = (__bf16)((qf + cbp[e]) * LOG2E);
            qp[e] = (__bf16)((qf + pbp[e]) * LOG2E);
        }
        qcF[kc] = qc; qpF[kc] = qp;
    }

    // ---- rel tables via MFMA: C[fm][i] = Wsuf[fm] . qp[i]  (log2 domain) ----
    f32x16 rP = zero16(), rM = zero16();
    #pragma unroll
    for (int kc = 0; kc < 4; ++kc){
        bf16x8 aP = ldfrag(&WsPs[l31 * 72 + kc * 16 + h8]);
        bf16x8 aM = ldfrag(&WsMs[l31 * 72 + kc * 16 + h8]);
        rP = __builtin_amdgcn_mfma_f32_32x32x16_bf16(aP, qpF[kc], rP, 0, 0, 0);
        rM = __builtin_amdgcn_mfma_f32_32x32x16_bf16(aM, qpF[kc], rM, 0, 0, 0);
    }
    __syncthreads();   // all LDS reads (Qs, Wsuf) done before overwrites

    // fm==0 happens only at dd==0 (cw_1 > 0), so slot 0 stores the d==0
    // value (s1 only) and the slow path indexes by fm with NO select.
    #pragma unroll
    for (int r = 0; r < 16; ++r){
        int fm = (r & 3) + 8 * (r >> 2) + 4 * hbit;
        relP[i_loc * 34 + fm] = f2b(rP[r]);
        relM[i_loc * 34 + fm] = f2b(rM[r]);
    }
    if (hbit == 0)
        relP[i_loc * 34 + 0] = f2b((rP[0] + rM[0]) * 0.5f);  // d==0: s1
    STORE();           // K/V tile 0 into seg0 (Qs dead)
    __syncthreads();

    // ---- main K-loop ----
    float mrow = -1e30f, lacc = 0.f;
    f32x16 oacc0 = zero16(), oacc1 = zero16();

#define MFMA32(A, B, C) __builtin_amdgcn_mfma_f32_32x32x16_bf16(A, B, C, 0, 0, 0)

#define PACK8(ST, WD) { \
    _Pragma("unroll") \
    for (int q_ = 0; q_ < 8; ++q_){ \
        float pa_ = EXP2(ST[2 * q_]     - bias); \
        float pc_ = EXP2(ST[2 * q_ + 1] - bias); \
        lsum += pa_ + pc_; \
        WD[q_] = (unsigned int)f2b(pa_) | ((unsigned int)f2b(pc_) << 16); \
    } }

    // halved-shuffle fragment build: send (hbit ? a : b), receive the
    // other half's counterpart; 2 shuffles per fragment instead of 4.
#define MKFRAG(DST, WD, ZZ) { \
    unsigned int a0_ = WD[(ZZ) * 4 + 0], a1_ = WD[(ZZ) * 4 + 1]; \
    unsigned int b0_ = WD[(ZZ) * 4 + 2], b1_ = WD[(ZZ) * 4 + 3]; \
    unsigned int sh0_ = (unsigned int)__shfl_xor((int)(hbit ? a0_ : b0_), 32); \
    unsigned int sh1_ = (unsigned int)__shfl_xor((int)(hbit ? a1_ : b1_), 32); \
    u32x4 fw_; \
    fw_[0] = hbit ? sh0_ : a0_; \
    fw_[1] = hbit ? sh1_ : a1_; \
    fw_[2] = hbit ? b0_  : sh0_; \
    fw_[3] = hbit ? b1_  : sh1_; \
    DST = __builtin_bit_cast(bf16x8, fw_); }

#define PVSTEP(PF, COL) { \
    oacc0 = MFMA32(PF, ldfrag(&Vts[(l31)      * 72 + (COL) + h8]), oacc0); \
    oacc1 = MFMA32(PF, ldfrag(&Vts[(32 + l31) * 72 + (COL) + h8]), oacc1); }

    const u16* relP_i = relP + i_loc * 34;
    const u16* relM_i = relM + i_loc * 34;

    for (int kt = 0; kt < NT; ++kt){
        int j0 = jbase + kt * 64;
        if (kt + 1 < NT) LOAD(j0 + 64);

        // S^T = K . Q^T : st0 = rows j 0..31, st1 = rows j 32..63; col i = lane&31
        f32x16 st0 = zero16(), st1 = zero16();
        __builtin_amdgcn_s_setprio(1);
        #pragma unroll
        for (int kc = 0; kc < 4; ++kc){
            bf16x8 k0 = ldfrag(&Ks[(l31)      * 72 + kc * 16 + h8]);
            bf16x8 k1 = ldfrag(&Ks[(32 + l31) * 72 + kc * 16 + h8]);
            st0 = MFMA32(k0, qcF[kc], st0);
            st1 = MFMA32(k1, qcF[kc], st1);
        }
        __builtin_amdgcn_s_setprio(0);

        // rel merge: fast path keeps st raw and folds relv into the exp bias
        int D = j0 - i0;
        int Di = D - i_loc;
        float relv = 0.f;
        bool fast = false; int fmU = 0; const u16* tabU = relP_i;
        if (D >= 128){
            int fa = fmt[D - 127], fb = fmt[D + 63];
            fast = (fa == fb); fmU = fa; tabU = relP_i;
        } else if (D <= -64){
            int fa = fmt[-D - 63], fb = fmt[-D + 127];
            fast = (fa == fb); fmU = fa; tabU = relM_i;
        }
        if (fast){
            relv = b2f(tabU[fmU]);
        } else {
            #pragma unroll
            for (int r = 0; r < 16; ++r){
                const int jb = (r & 3) + 8 * (r >> 2);
                int jbh = jb + 4 * hbit;
                {
                    int dd = Di + jbh;
                    int ad = dd < 0 ? -dd : dd;
                    int fm = fmt[ad];
                    const u16* tab = (dd >= 0) ? relP_i : relM_i;
                    st0[r] += b2f(tab[fm]);
                }
                {
                    int dd = Di + 32 + jbh;
                    int ad = dd < 0 ? -dd : dd;
                    int fm = fmt[ad];
                    const u16* tab = (dd >= 0) ? relP_i : relM_i;
                    st1[r] += b2f(tab[fm]);
                }
            }
        }

        // row max (lane-local + one cross-half shuffle); relv added once
        float mx = st0[0];
        #pragma unroll
        for (int r = 1; r < 16; ++r) mx = fmaxf(mx, st0[r]);
        #pragma unroll
        for (int r = 0; r < 16; ++r) mx = fmaxf(mx, st1[r]);
        mx = fmaxf(mx, __shfl_xor(mx, 32)) + relv;

        // defer-max (log2 domain, THR = 11 ~ e^7.6)
        if (!__all(mx - mrow <= 11.0f)){
            float mnew = fmaxf(mrow, mx);
            float alpha = EXP2(mrow - mnew);
            mrow = mnew;
            lacc *= alpha;
            #pragma unroll
            for (int r = 0; r < 16; ++r){
                float ar = __shfl(alpha, (r & 3) + 8 * (r >> 2) + 4 * hbit);
                oacc0[r] *= ar; oacc1[r] *= ar;
            }
        }

        // P = exp2(st - bias), bias = mrow - relv; l from unrounded floats
        float bias = mrow - relv;
        float lsum = 0.f;
        unsigned int wds0[8], wds1[8];
        PACK8(st0, wds0)
        PACK8(st1, wds1)
        lacc += lsum + __shfl_xor(lsum, 32);

        // in-register transpose to PV A-fragments (rows i = lane&31)
        bf16x8 pf0, pf1, pf2, pf3;
        MKFRAG(pf0, wds0, 0)   // j  0..15
        MKFRAG(pf1, wds0, 1)   // j 16..31
        MKFRAG(pf2, wds1, 0)   // j 32..47
        MKFRAG(pf3, wds1, 1)   // j 48..63
        __builtin_amdgcn_s_setprio(1);
        PVSTEP(pf0,  0)
        PVSTEP(pf1, 16)
        PVSTEP(pf2, 32)
        PVSTEP(pf3, 48)
        __builtin_amdgcn_s_setprio(0);

        __syncthreads();
        if (kt + 1 < NT) STORE();
        __syncthreads();
    }

    // ---- write partials ----
    size_t pb = ((size_t)half * 128 + bid) * 128;
    #pragma unroll
    for (int r = 0; r < 16; ++r){
        int iO = w * 32 + (r & 3) + 8 * (r >> 2) + 4 * hbit;
        OpU[(pb + iO) * 64 + l31]      = f2b(oacc0[r]);
        OpU[(pb + iO) * 64 + 32 + l31] = f2b(oacc1[r]);
    }
    if (hbit == 0){
        mpart[pb + i_loc] = mrow;
        lpart[pb + i_loc] = lacc;
    }
#undef MFMA32
#undef PACK8
#undef MKFRAG
#undef PVSTEP
}

// ---------------------------------------------------------------------------
// Combine 8 K-eighths -> normalized bf16 Oatt (log2-domain partial maxima).
// ---------------------------------------------------------------------------
__global__ __launch_bounds__(256) void combine_kernel(const u16* __restrict__ OpU,
    const float* __restrict__ mpart, const float* __restrict__ lpart,
    u16* __restrict__ Oatt){
    int i0 = blockIdx.x * 128;
    int h  = blockIdx.y;
    int bid = blockIdx.x * NH + h;
    int t = threadIdx.x;
    int r = t >> 1, cb = (t & 1) * 32;
    size_t pr[8];
    float ms[8], ls[8];
    float m = -1e30f;
    #pragma unroll
    for (int s = 0; s < 8; ++s){
        pr[s] = ((size_t)s * 128 + bid) * 128 + r;
        ms[s] = mpart[pr[s]];
        ls[s] = lpart[pr[s]];
        m = fmaxf(m, ms[s]);
    }
    float den = 0.f, wgt[8];
    #pragma unroll
    for (int s = 0; s < 8; ++s){ wgt[s] = EXP2(ms[s] - m); den += wgt[s] * ls[s]; }
    float inv = 1.0f / fmaxf(den, 1e-30f);
    float o[32];
    #pragma unroll
    for (int e = 0; e < 32; ++e) o[e] = 0.f;
    #pragma unroll
    for (int s = 0; s < 8; ++s){
        #pragma unroll
        for (int c = 0; c < 4; ++c){
            u16x8 a = *(const u16x8*)&OpU[pr[s] * 64 + cb + c * 8];
            #pragma unroll
            for (int e = 0; e < 8; ++e) o[c * 8 + e] += wgt[s] * b2f(a[e]);
        }
    }
    size_t ob = (size_t)(i0 + r) * HD + h * DK + cb;
    #pragma unroll
    for (int c = 0; c < 4; ++c){
        u16x8 rv;
        #pragma unroll
        for (int e = 0; e < 8; ++e) rv[e] = f2b(o[c * 8 + e] * inv);
        *(u16x8*)&Oatt[ob + c * 8] = rv;
    }
}

// ---------------------------------------------------------------------------
// Output projection: out = Oattn @ Wo + bo (fp32 W/bias/out). Unchanged.
// ---------------------------------------------------------------------------
__global__ __launch_bounds__(256) void oproj_kernel(const u16* __restrict__ A,
    const float* __restrict__ Wo, const float* __restrict__ bo,
    float* __restrict__ out, int m_base){
    __shared__ __align__(16) u16 xs[64 * 72];
    __shared__ __align__(16) u16 bs[64 * 72];
    int m0 = m_base + blockIdx.y * 64;
    int n0 = blockIdx.x * 64;
    int t = threadIdx.x;
    int w = t >> 6, lane = t & 63, qd = lane >> 4, l15 = lane & 15;
    f32x4 acc[4] = {{0,0,0,0},{0,0,0,0},{0,0,0,0},{0,0,0,0}};
    for (int k0 = 0; k0 < HD; k0 += 64){
        #pragma unroll
        for (int rep = 0; rep < 2; ++rep){
            int vid = rep * 256 + t;
            int r  = vid >> 3;
            int cv = (vid & 7) * 8;
            *(u16x8*)&xs[r * 72 + cv] = *(const u16x8*)&A[(size_t)(m0 + r) * HD + k0 + cv];
            size_t wi = (size_t)(k0 + r) * DIMM + n0 + cv;
            f32x4 wa = *(const f32x4*)(Wo + wi), wb = *(const f32x4*)(Wo + wi + 4);
            u16x8 wv;
            #pragma unroll
            for (int e = 0; e < 4; ++e){ wv[e] = f2b(wa[e]); wv[4 + e] = f2b(wb[e]); }
            #pragma unroll
            for (int e = 0; e < 8; ++e) bs[(cv + e) * 72 + r] = wv[e];
        }
        __syncthreads();
        bf16x8 a0 = ldfrag(&xs[(w * 16 + l15) * 72 +  0 + qd * 8]);
        bf16x8 a1 = ldfrag(&xs[(w * 16 + l15) * 72 + 32 + qd * 8]);
        #pragma unroll
        for (int nt = 0; nt < 4; ++nt){
            bf16x8 b0 = ldfrag(&bs[(nt * 16 + l15) * 72 +  0 + qd * 8]);
            bf16x8 b1 = ldfrag(&bs[(nt * 16 + l15) * 72 + 32 + qd * 8]);
            acc[nt] = __builtin_amdgcn_mfma_f32_16x16x32_bf16(a0, b0, acc[nt], 0, 0, 0);
            acc[nt] = __builtin_amdgcn_mfma_f32_16x16x32_bf16(a1, b1, acc[nt], 0, 0, 0);
        }
        __syncthreads();
    }
    #pragma unroll
    for (int nt = 0; nt < 4; ++nt)
        #pragma unroll
        for (int reg = 0; reg < 4; ++reg){
            int row = m0 + w * 16 + qd * 4 + reg;
            int col = n0 + nt * 16 + l15;
            out[(size_t)row * DIMM + col] = acc[nt][reg] + bo[col];
        }
}

extern "C" void kernel_launch(void* const* d_in, const int* in_sizes, int n_in,
                              void* d_out, int out_size, void* d_ws, size_t ws_size,
                              hipStream_t stream){
    const float* X  = (const float*)d_in[0];
    const float* Wq = (const float*)d_in[1];
    const float* Wk = (const float*)d_in[2];
    const float* Wv = (const float*)d_in[3];
    const float* Wr = (const float*)d_in[4];
    const float* Wo = (const float*)d_in[5];
    const float* bo = (const float*)d_in[6];
    const float* CB = (const float*)d_in[7];
    const float* PB = (const float*)d_in[8];
    float* out = (float*)d_out;
    u16* base = (u16*)d_out;   // 12,582,912 u16 slots

    // d_out scratch layout (u16 offsets):
    //   Qb   [0, 1048576)          (Oatt overlays this after attn)
    //   Kb   [1048576, 2097152)
    //   Vt   [2097152, 3145728)
    //   Wt   [3145728, 4325376)    dead after qkv; OpU overlays it:
    //   OpU  [3145728, 11534336)   8 splits x 128 bid x 128 rows x 64
    //   mpart f32 @ u16 [11534336, 11796480), lpart [11796480, 12058624)
    u16* Qb   = base;
    u16* Kb   = base + 1048576;
    u16* Vt   = base + 2097152;
    u16* Wt   = base + 3145728;
    u16* OpU  = base + 3145728;
    float* mpart = out + 5767168;
    float* lpart = out + 5898240;
    u16* Oatt = base;              // overlays Qb (dead after attn)

    unsigned char* fmtg = (unsigned char*)d_ws;
    u16* WsP = (u16*)((char*)d_ws + 4096);    // 4h x 32 x 64 bf16 = 16384 B
    u16* WsM = (u16*)((char*)d_ws + 20480);   // 16384 B

    convwt_kernel<<<dim3(576), 256, 0, stream>>>(Wq, Wk, Wv, Wt);
    fmtab_kernel<<<dim3(17), 256, 0, stream>>>(fmtg, Wr, WsP, WsM);
    qkv_kernel<<<dim3(12, 64), 256, 0, stream>>>(X, Wt, Qb, Kb, Vt);
    attn_kernel<<<dim3(32, NH, KSPLIT), 256, 0, stream>>>(Qb, Kb, Vt, WsP, WsM,
                                                          fmtg, CB, PB,
                                                          OpU, mpart, lpart);
    combine_kernel<<<dim3(32, NH), 256, 0, stream>>>(OpU, mpart, lpart, Oatt);

    // oproj in DESCENDING row order so out-writes (u16-view 3072/row) never
    // clobber Oatt rows (256/row) still to be read:
    //   [384,4096): writes start at u16 1,179,648 > Oatt end 1,048,576 — safe.
    //   [64,384):   writes [196608,..) > its own read region [16384, 98304).
    //   [0,64):     single block; reads complete before epilogue writes.
    oproj_kernel<<<dim3(24, 58), 256, 0, stream>>>(Oatt, Wo, bo, out, 384);
    oproj_kernel<<<dim3(24,  5), 256, 0, stream>>>(Oatt, Wo, bo, out, 64);
    oproj_kernel<<<dim3(24,  1), 256, 0, stream>>>(Oatt, Wo, bo, out, 0);
}

// Round 5
// 223.295 us; speedup vs baseline: 1.2725x; 1.0283x over previous
//
#include <hip/hip_runtime.h>
#include <hip/hip_bf16.h>

#define N_SEQ 4096
#define DIMM  1536
#define NH    4
#define DK    64
#define HD    256     // NH*DK
#define QK_SCALE 0.125f
#define WSZ   393216  // 1536*256 per weight
#define KSPLIT 8
#define LOG2E 1.44269504f

typedef __bf16 bf16x8 __attribute__((ext_vector_type(8)));
typedef unsigned short u16;
typedef u16   u16x8  __attribute__((ext_vector_type(8)));
typedef u16   u16x4  __attribute__((ext_vector_type(4)));
typedef float f32x4  __attribute__((ext_vector_type(4)));
typedef float f32x16 __attribute__((ext_vector_type(16)));
typedef unsigned int u32x4 __attribute__((ext_vector_type(4)));

__device__ inline float b2f(u16 u){
    union { float f; unsigned int i; } v; v.i = ((unsigned int)u) << 16; return v.f;
}
__device__ inline u16 f2b(float f){
    __bf16 h = (__bf16)f;               // native cvt, RNE
    return __builtin_bit_cast(u16, h);
}
__device__ inline bf16x8 ldfrag(const u16* p){
    return __builtin_bit_cast(bf16x8, *(const u16x8*)p);
}
__device__ inline f32x16 zero16(){
    f32x16 v;
    #pragma unroll
    for (int i = 0; i < 16; ++i) v[i] = 0.f;
    return v;
}
#define EXP2(x) exp2f(x)   // lowers to a single v_exp_f32 on gfx950

// ---------------------------------------------------------------------------
// Convert Wq|Wk|Wv (fp32, [k][n]) -> Wt (bf16, TRANSPOSED [n][k]) via LDS
// transpose: coalesced reads AND writes, fp32 [64][65] staging (2-way banks).
// ---------------------------------------------------------------------------
__global__ __launch_bounds__(256) void convwt_kernel(const float* __restrict__ Wq,
    const float* __restrict__ Wk, const float* __restrict__ Wv, u16* __restrict__ Wt){
    __shared__ float T[64 * 65];
    int bid = blockIdx.x;          // 288 = 3 s x 96 tiles
    int s = bid / 96, tile = bid % 96;
    int n0 = (tile / 24) * 64;     // 4 n-tiles (HD=256)
    int k0 = (tile % 24) * 64;     // 24 k-tiles (DIMM=1536)
    const float* W = (s == 0) ? Wq : (s == 1 ? Wk : Wv);
    int t = threadIdx.x;
    int rA = t >> 3, c8 = (t & 7) * 8;
    #pragma unroll
    for (int rep = 0; rep < 2; ++rep){
        int rr = rep * 32 + rA;
        const float* p = W + (size_t)(k0 + rr) * HD + n0 + c8;
        f32x4 a = *(const f32x4*)p, b = *(const f32x4*)(p + 4);
        #pragma unroll
        for (int e = 0; e < 4; ++e){
            T[rr * 65 + c8 + e]     = a[e];
            T[rr * 65 + c8 + 4 + e] = b[e];
        }
    }
    __syncthreads();
    #pragma unroll
    for (int rep = 0; rep < 2; ++rep){
        int rn = rep * 32 + rA;
        u16x8 o;
        #pragma unroll
        for (int e = 0; e < 8; ++e) o[e] = f2b(T[(c8 + e) * 65 + rn]);
        *(u16x8*)&Wt[(size_t)s * WSZ + (size_t)(n0 + rn) * DIMM + k0 + c8] = o;
    }
}

// ---------------------------------------------------------------------------
// fmtab[ad] = #{f in [0,32): cw[f] <= ad}; block 16 does the suffix-summed
// rel-position weights (wsuf) with all loads issued up-front (one latency).
// ---------------------------------------------------------------------------
__global__ __launch_bounds__(256) void fmtab_kernel(unsigned char* __restrict__ fmt,
    const float* __restrict__ Wrel, u16* __restrict__ WsP, u16* __restrict__ WsM){
    int t = threadIdx.x;
    if (blockIdx.x == 16){
        int h = t >> 6, d = t & 63;
        float w1[32], w2[32];
        #pragma unroll
        for (int fm = 0; fm < 32; ++fm){
            w1[fm] = Wrel[(size_t)fm * HD + h * DK + d];
            w2[fm] = Wrel[(size_t)(32 + fm) * HD + h * DK + d];
        }
        float a1 = 0.f, a2 = 0.f;
        #pragma unroll
        for (int fm = 31; fm >= 0; --fm){
            a1 += w1[fm];
            a2 += w2[fm];
            WsP[(h * 32 + fm) * 64 + d] = f2b(a1 + a2);
            WsM[(h * 32 + fm) * 64 + d] = f2b(a1 - a2);
        }
        return;
    }
    int d = blockIdx.x * 256 + t;                     // 16 blocks
    float lg = logf((float)(N_SEQ + 1)) * (1.0f / 32.0f);
    float ad = (float)d;
    int fm = 0;
    for (int f = 0; f < 32; ++f){
        float cw = expf(lg * (float)(f + 1)) - 1.0f;
        fm += (cw <= ad) ? 1 : 0;
    }
    fmt[d] = (unsigned char)fm;
}

// ---------------------------------------------------------------------------
// QKV projection: per-projection blocks (grid 12 x 64 = 768 blocks) +
// register-prefetch 2-phase pipeline. (unchanged)
// ---------------------------------------------------------------------------
__global__ __launch_bounds__(256) void qkv_kernel(const float* __restrict__ X,
    const u16* __restrict__ Wt,
    u16* __restrict__ Q, u16* __restrict__ K, u16* __restrict__ Vt){
    __shared__ __align__(16) u16 xs[64 * 72];
    __shared__ __align__(16) u16 bs[64 * 72];
    int s  = blockIdx.x >> 2;             // 0:Q 1:K 2:V
    int n0 = (blockIdx.x & 3) * 64;
    int m0 = blockIdx.y * 64;
    int t = threadIdx.x;
    int w = t >> 6, lane = t & 63, qd = lane >> 4, l15 = lane & 15;
    int r  = t >> 3;                      // staging row 0..31 (+32 on rep 1)
    int cv = (t & 7) * 8;                 // staging col
    f32x4 acc[4] = {{0,0,0,0},{0,0,0,0},{0,0,0,0},{0,0,0,0}};

    f32x4 xa[2], xb[2];
    u16x8 wv[2];
    auto LOAD = [&](int k0){
        #pragma unroll
        for (int rep = 0; rep < 2; ++rep){
            int rr = rep * 32 + r;
            size_t xi = (size_t)(m0 + rr) * DIMM + k0 + cv;
            xa[rep] = *(const f32x4*)(X + xi);
            xb[rep] = *(const f32x4*)(X + xi + 4);
            wv[rep] = *(const u16x8*)&Wt[(size_t)s * WSZ + (size_t)(n0 + rr) * DIMM + k0 + cv];
        }
    };
    auto STORE = [&](){
        #pragma unroll
        for (int rep = 0; rep < 2; ++rep){
            int rr = rep * 32 + r;
            u16x8 xv;
            #pragma unroll
            for (int e = 0; e < 4; ++e){ xv[e] = f2b(xa[rep][e]); xv[4 + e] = f2b(xb[rep][e]); }
            *(u16x8*)&xs[rr * 72 + cv] = xv;
            *(u16x8*)&bs[rr * 72 + cv] = wv[rep];
        }
    };

    LOAD(0);
    for (int k0 = 0; k0 < DIMM; k0 += 64){
        STORE();
        __syncthreads();
        if (k0 + 64 < DIMM) LOAD(k0 + 64);
        bf16x8 a0 = ldfrag(&xs[(w * 16 + l15) * 72 +  0 + qd * 8]);
        bf16x8 a1 = ldfrag(&xs[(w * 16 + l15) * 72 + 32 + qd * 8]);
        #pragma unroll
        for (int nt = 0; nt < 4; ++nt){
            bf16x8 b0 = ldfrag(&bs[(nt * 16 + l15) * 72 +  0 + qd * 8]);
            bf16x8 b1 = ldfrag(&bs[(nt * 16 + l15) * 72 + 32 + qd * 8]);
            acc[nt] = __builtin_amdgcn_mfma_f32_16x16x32_bf16(a0, b0, acc[nt], 0, 0, 0);
            acc[nt] = __builtin_amdgcn_mfma_f32_16x16x32_bf16(a1, b1, acc[nt], 0, 0, 0);
        }
        __syncthreads();
    }

    int row0 = m0 + w * 16 + qd * 4;
    if (s == 0){
        #pragma unroll
        for (int nt = 0; nt < 4; ++nt){
            int col = n0 + nt * 16 + l15;
            #pragma unroll
            for (int reg = 0; reg < 4; ++reg)
                Q[(size_t)(row0 + reg) * HD + col] = f2b(acc[nt][reg] * QK_SCALE);
        }
    } else if (s == 1){
        #pragma unroll
        for (int nt = 0; nt < 4; ++nt){
            int col = n0 + nt * 16 + l15;
            #pragma unroll
            for (int reg = 0; reg < 4; ++reg)
                K[(size_t)(row0 + reg) * HD + col] = f2b(acc[nt][reg]);
        }
    } else {
        #pragma unroll
        for (int nt = 0; nt < 4; ++nt){
            int col = n0 + nt * 16 + l15;
            u16x4 pv;
            #pragma unroll
            for (int reg = 0; reg < 4; ++reg) pv[reg] = f2b(acc[nt][reg]);
            *(u16x4*)&Vt[(size_t)col * N_SEQ + row0] = pv;
        }
    }
}

// ---------------------------------------------------------------------------
// Flash attention (unchanged from round 4).
// ---------------------------------------------------------------------------
__global__ __launch_bounds__(256) void attn_kernel(const u16* __restrict__ Q,
    const u16* __restrict__ Kg, const u16* __restrict__ Vt,
    const u16* __restrict__ WsPg, const u16* __restrict__ WsMg,
    const unsigned char* __restrict__ fmtg,
    const float* __restrict__ CB, const float* __restrict__ PB,
    u16* __restrict__ OpU, float* __restrict__ mpart, float* __restrict__ lpart){
    __shared__ __align__(16) unsigned char smem[39936];
    u16* Ks   = (u16*)(smem);             // [64][72]  main loop
    u16* Vts  = (u16*)(smem + 9216);      // [64][72]  main loop
    u16* Qs   = (u16*)(smem);             // init alias: [128][72]
    u16* relP = (u16*)(smem + 18432);     // [128][34] u16 (slot 0 = d==0 value)
    u16* relM = (u16*)(smem + 27136);     // [128][34] u16
    unsigned char* fmt = smem + 35840;    // 4096
    u16* WsPs = (u16*)(smem + 18432);     // init alias: [32][72]
    u16* WsMs = (u16*)(smem + 23040);     // init alias: [32][72]

    int i0   = blockIdx.x * 128;
    int h    = blockIdx.y;
    int half = blockIdx.z;                // 0..7
    int bid  = blockIdx.x * NH + h;       // 0..127
    int jbase = half * (N_SEQ / KSPLIT);
    const int NT = (N_SEQ / KSPLIT) / 64; // 8 tiles
    int t = threadIdx.x;
    int w = t >> 6, lane = t & 63, l31 = lane & 31, hbit = lane >> 5;
    int h8 = hbit * 8;
    int i_loc = w * 32 + l31;             // this lane's softmax row (block-local)

    int sr = t >> 3, scv = (t & 7) * 8;
    u16x8 kr0, kr1, vr0, vr1;
    auto LOAD = [&](int j0){
        kr0 = *(const u16x8*)&Kg[(size_t)(j0 + sr)      * HD + h * DK + scv];
        kr1 = *(const u16x8*)&Kg[(size_t)(j0 + 32 + sr) * HD + h * DK + scv];
        vr0 = *(const u16x8*)&Vt[(size_t)(h * 64 + sr)      * N_SEQ + j0 + scv];
        vr1 = *(const u16x8*)&Vt[(size_t)(h * 64 + 32 + sr) * N_SEQ + j0 + scv];
    };
    auto STORE = [&](){
        *(u16x8*)&Ks [(sr)      * 72 + scv] = kr0;
        *(u16x8*)&Ks [(32 + sr) * 72 + scv] = kr1;
        *(u16x8*)&Vts[(sr)      * 72 + scv] = vr0;
        *(u16x8*)&Vts[(32 + sr) * 72 + scv] = vr1;
    };
    LOAD(jbase);

    // ---- init staging: Q rows (raw bf16), Wsuf slices, fmt ----
    #pragma unroll
    for (int rep = 0; rep < 4; ++rep){
        int vid = rep * 256 + t;
        int r  = vid >> 3;
        int cv = (vid & 7) * 8;
        *(u16x8*)&Qs[r * 72 + cv] = *(const u16x8*)&Q[(size_t)(i0 + r) * HD + h * DK + cv];
    }
    {
        int r = t >> 3, cv = (t & 7) * 8;
        *(u16x8*)&WsPs[r * 72 + cv] = *(const u16x8*)&WsPg[(h * 32 + r) * 64 + cv];
        *(u16x8*)&WsMs[r * 72 + cv] = *(const u16x8*)&WsMg[(h * 32 + r) * 64 + cv];
    }
    ((uint4*)fmt)[t] = ((const uint4*)fmtg)[t];
    __syncthreads();

    // ---- per-lane Q fragments (B-operand layout), bias + LOG2E folded ----
    bf16x8 qcF[4], qpF[4];
    #pragma unroll
    for (int kc = 0; kc < 4; ++kc){
        bf16x8 raw = ldfrag(&Qs[i_loc * 72 + kc * 16 + h8]);
        const float* cbp = CB + h * DK + kc * 16 + h8;
        const float* pbp = PB + h * DK + kc * 16 + h8;
        bf16x8 qc, qp;
        #pragma unroll
        for (int e = 0; e < 8; ++e){
            float qf = (float)raw[e];
            qc[e] = (__bf16)((qf + cbp[e]) * LOG2E);
            qp[e] = (__bf16)((qf + pbp[e]) * LOG2E);
        }
        qcF[kc] = qc; qpF[kc] = qp;
    }

    // ---- rel tables via MFMA: C[fm][i] = Wsuf[fm] . qp[i]  (log2 domain) ----
    f32x16 rP = zero16(), rM = zero16();
    #pragma unroll
    for (int kc = 0; kc < 4; ++kc){
        bf16x8 aP = ldfrag(&WsPs[l31 * 72 + kc * 16 + h8]);
        bf16x8 aM = ldfrag(&WsMs[l31 * 72 + kc * 16 + h8]);
        rP = __builtin_amdgcn_mfma_f32_32x32x16_bf16(aP, qpF[kc], rP, 0, 0, 0);
        rM = __builtin_amdgcn_mfma_f32_32x32x16_bf16(aM, qpF[kc], rM, 0, 0, 0);
    }
    __syncthreads();   // all LDS reads (Qs, Wsuf) done before overwrites

    // fm==0 happens only at dd==0 (cw_1 > 0), so slot 0 stores the d==0
    // value (s1 only) and the slow path indexes by fm with NO select.
    #pragma unroll
    for (int r = 0; r < 16; ++r){
        int fm = (r & 3) + 8 * (r >> 2) + 4 * hbit;
        relP[i_loc * 34 + fm] = f2b(rP[r]);
        relM[i_loc * 34 + fm] = f2b(rM[r]);
    }
    if (hbit == 0)
        relP[i_loc * 34 + 0] = f2b((rP[0] + rM[0]) * 0.5f);  // d==0: s1
    STORE();           // K/V tile 0 into seg0 (Qs dead)
    __syncthreads();

    // ---- main K-loop ----
    float mrow = -1e30f, lacc = 0.f;
    f32x16 oacc0 = zero16(), oacc1 = zero16();

#define MFMA32(A, B, C) __builtin_amdgcn_mfma_f32_32x32x16_bf16(A, B, C, 0, 0, 0)

#define PACK8(ST, WD) { \
    _Pragma("unroll") \
    for (int q_ = 0; q_ < 8; ++q_){ \
        float pa_ = EXP2(ST[2 * q_]     - bias); \
        float pc_ = EXP2(ST[2 * q_ + 1] - bias); \
        lsum += pa_ + pc_; \
        WD[q_] = (unsigned int)f2b(pa_) | ((unsigned int)f2b(pc_) << 16); \
    } }

    // halved-shuffle fragment build: send (hbit ? a : b), receive the
    // other half's counterpart; 2 shuffles per fragment instead of 4.
#define MKFRAG(DST, WD, ZZ) { \
    unsigned int a0_ = WD[(ZZ) * 4 + 0], a1_ = WD[(ZZ) * 4 + 1]; \
    unsigned int b0_ = WD[(ZZ) * 4 + 2], b1_ = WD[(ZZ) * 4 + 3]; \
    unsigned int sh0_ = (unsigned int)__shfl_xor((int)(hbit ? a0_ : b0_), 32); \
    unsigned int sh1_ = (unsigned int)__shfl_xor((int)(hbit ? a1_ : b1_), 32); \
    u32x4 fw_; \
    fw_[0] = hbit ? sh0_ : a0_; \
    fw_[1] = hbit ? sh1_ : a1_; \
    fw_[2] = hbit ? b0_  : sh0_; \
    fw_[3] = hbit ? b1_  : sh1_; \
    DST = __builtin_bit_cast(bf16x8, fw_); }

#define PVSTEP(PF, COL) { \
    oacc0 = MFMA32(PF, ldfrag(&Vts[(l31)      * 72 + (COL) + h8]), oacc0); \
    oacc1 = MFMA32(PF, ldfrag(&Vts[(32 + l31) * 72 + (COL) + h8]), oacc1); }

    const u16* relP_i = relP + i_loc * 34;
    const u16* relM_i = relM + i_loc * 34;

    for (int kt = 0; kt < NT; ++kt){
        int j0 = jbase + kt * 64;
        if (kt + 1 < NT) LOAD(j0 + 64);

        // S^T = K . Q^T : st0 = rows j 0..31, st1 = rows j 32..63; col i = lane&31
        f32x16 st0 = zero16(), st1 = zero16();
        __builtin_amdgcn_s_setprio(1);
        #pragma unroll
        for (int kc = 0; kc < 4; ++kc){
            bf16x8 k0 = ldfrag(&Ks[(l31)      * 72 + kc * 16 + h8]);
            bf16x8 k1 = ldfrag(&Ks[(32 + l31) * 72 + kc * 16 + h8]);
            st0 = MFMA32(k0, qcF[kc], st0);
            st1 = MFMA32(k1, qcF[kc], st1);
        }
        __builtin_amdgcn_s_setprio(0);

        // rel merge: fast path keeps st raw and folds relv into the exp bias
        int D = j0 - i0;
        int Di = D - i_loc;
        float relv = 0.f;
        bool fast = false; int fmU = 0; const u16* tabU = relP_i;
        if (D >= 128){
            int fa = fmt[D - 127], fb = fmt[D + 63];
            fast = (fa == fb); fmU = fa; tabU = relP_i;
        } else if (D <= -64){
            int fa = fmt[-D - 63], fb = fmt[-D + 127];
            fast = (fa == fb); fmU = fa; tabU = relM_i;
        }
        if (fast){
            relv = b2f(tabU[fmU]);
        } else {
            #pragma unroll
            for (int r = 0; r < 16; ++r){
                const int jb = (r & 3) + 8 * (r >> 2);
                int jbh = jb + 4 * hbit;
                {
                    int dd = Di + jbh;
                    int ad = dd < 0 ? -dd : dd;
                    int fm = fmt[ad];
                    const u16* tab = (dd >= 0) ? relP_i : relM_i;
                    st0[r] += b2f(tab[fm]);
                }
                {
                    int dd = Di + 32 + jbh;
                    int ad = dd < 0 ? -dd : dd;
                    int fm = fmt[ad];
                    const u16* tab = (dd >= 0) ? relP_i : relM_i;
                    st1[r] += b2f(tab[fm]);
                }
            }
        }

        // row max (lane-local + one cross-half shuffle); relv added once
        float mx = st0[0];
        #pragma unroll
        for (int r = 1; r < 16; ++r) mx = fmaxf(mx, st0[r]);
        #pragma unroll
        for (int r = 0; r < 16; ++r) mx = fmaxf(mx, st1[r]);
        mx = fmaxf(mx, __shfl_xor(mx, 32)) + relv;

        // defer-max (log2 domain, THR = 11 ~ e^7.6)
        if (!__all(mx - mrow <= 11.0f)){
            float mnew = fmaxf(mrow, mx);
            float alpha = EXP2(mrow - mnew);
            mrow = mnew;
            lacc *= alpha;
            #pragma unroll
            for (int r = 0; r < 16; ++r){
                float ar = __shfl(alpha, (r & 3) + 8 * (r >> 2) + 4 * hbit);
                oacc0[r] *= ar; oacc1[r] *= ar;
            }
        }

        // P = exp2(st - bias), bias = mrow - relv; l from unrounded floats
        float bias = mrow - relv;
        float lsum = 0.f;
        unsigned int wds0[8], wds1[8];
        PACK8(st0, wds0)
        PACK8(st1, wds1)
        lacc += lsum + __shfl_xor(lsum, 32);

        // in-register transpose to PV A-fragments (rows i = lane&31)
        bf16x8 pf0, pf1, pf2, pf3;
        MKFRAG(pf0, wds0, 0)   // j  0..15
        MKFRAG(pf1, wds0, 1)   // j 16..31
        MKFRAG(pf2, wds1, 0)   // j 32..47
        MKFRAG(pf3, wds1, 1)   // j 48..63
        __builtin_amdgcn_s_setprio(1);
        PVSTEP(pf0,  0)
        PVSTEP(pf1, 16)
        PVSTEP(pf2, 32)
        PVSTEP(pf3, 48)
        __builtin_amdgcn_s_setprio(0);

        __syncthreads();
        if (kt + 1 < NT) STORE();
        __syncthreads();
    }

    // ---- write partials ----
    size_t pb = ((size_t)half * 128 + bid) * 128;
    #pragma unroll
    for (int r = 0; r < 16; ++r){
        int iO = w * 32 + (r & 3) + 8 * (r >> 2) + 4 * hbit;
        OpU[(pb + iO) * 64 + l31]      = f2b(oacc0[r]);
        OpU[(pb + iO) * 64 + 32 + l31] = f2b(oacc1[r]);
    }
    if (hbit == 0){
        mpart[pb + i_loc] = mrow;
        lpart[pb + i_loc] = lacc;
    }
#undef MFMA32
#undef PACK8
#undef MKFRAG
#undef PVSTEP
}

// ---------------------------------------------------------------------------
// Combine 8 K-eighths -> normalized bf16 Oatt. 4x more blocks (512), 8
// output elems/thread, one u16x8 read per split.
// ---------------------------------------------------------------------------
__global__ __launch_bounds__(256) void combine_kernel(const u16* __restrict__ OpU,
    const float* __restrict__ mpart, const float* __restrict__ lpart,
    u16* __restrict__ Oatt){
    int h = blockIdx.y;
    int t = threadIdx.x;
    int r = t >> 3, cb = (t & 7) * 8;
    int i = blockIdx.x * 32 + r;          // global row
    int bid = (i >> 7) * NH + h;
    int ri = i & 127;
    size_t pr[8];
    float ms[8], ls[8];
    float m = -1e30f;
    #pragma unroll
    for (int s = 0; s < 8; ++s){
        pr[s] = ((size_t)s * 128 + bid) * 128 + ri;
        ms[s] = mpart[pr[s]];
        ls[s] = lpart[pr[s]];
        m = fmaxf(m, ms[s]);
    }
    float den = 0.f, wgt[8];
    #pragma unroll
    for (int s = 0; s < 8; ++s){ wgt[s] = EXP2(ms[s] - m); den += wgt[s] * ls[s]; }
    float inv = 1.0f / fmaxf(den, 1e-30f);
    float o[8];
    #pragma unroll
    for (int e = 0; e < 8; ++e) o[e] = 0.f;
    #pragma unroll
    for (int s = 0; s < 8; ++s){
        u16x8 a = *(const u16x8*)&OpU[pr[s] * 64 + cb];
        #pragma unroll
        for (int e = 0; e < 8; ++e) o[e] += wgt[s] * b2f(a[e]);
    }
    u16x8 rv;
    #pragma unroll
    for (int e = 0; e < 8; ++e) rv[e] = f2b(o[e] * inv);
    *(u16x8*)&Oatt[(size_t)i * HD + h * DK + cb] = rv;
}

// ---------------------------------------------------------------------------
// Output projection: out = Oattn @ Wo + bo (fp32 W/bias/out). Unchanged.
// ---------------------------------------------------------------------------
__global__ __launch_bounds__(256) void oproj_kernel(const u16* __restrict__ A,
    const float* __restrict__ Wo, const float* __restrict__ bo,
    float* __restrict__ out, int m_base){
    __shared__ __align__(16) u16 xs[64 * 72];
    __shared__ __align__(16) u16 bs[64 * 72];
    int m0 = m_base + blockIdx.y * 64;
    int n0 = blockIdx.x * 64;
    int t = threadIdx.x;
    int w = t >> 6, lane = t & 63, qd = lane >> 4, l15 = lane & 15;
    f32x4 acc[4] = {{0,0,0,0},{0,0,0,0},{0,0,0,0},{0,0,0,0}};
    for (int k0 = 0; k0 < HD; k0 += 64){
        #pragma unroll
        for (int rep = 0; rep < 2; ++rep){
            int vid = rep * 256 + t;
            int r  = vid >> 3;
            int cv = (vid & 7) * 8;
            *(u16x8*)&xs[r * 72 + cv] = *(const u16x8*)&A[(size_t)(m0 + r) * HD + k0 + cv];
            size_t wi = (size_t)(k0 + r) * DIMM + n0 + cv;
            f32x4 wa = *(const f32x4*)(Wo + wi), wb = *(const f32x4*)(Wo + wi + 4);
            u16x8 wv;
            #pragma unroll
            for (int e = 0; e < 4; ++e){ wv[e] = f2b(wa[e]); wv[4 + e] = f2b(wb[e]); }
            #pragma unroll
            for (int e = 0; e < 8; ++e) bs[(cv + e) * 72 + r] = wv[e];
        }
        __syncthreads();
        bf16x8 a0 = ldfrag(&xs[(w * 16 + l15) * 72 +  0 + qd * 8]);
        bf16x8 a1 = ldfrag(&xs[(w * 16 + l15) * 72 + 32 + qd * 8]);
        #pragma unroll
        for (int nt = 0; nt < 4; ++nt){
            bf16x8 b0 = ldfrag(&bs[(nt * 16 + l15) * 72 +  0 + qd * 8]);
            bf16x8 b1 = ldfrag(&bs[(nt * 16 + l15) * 72 + 32 + qd * 8]);
            acc[nt] = __builtin_amdgcn_mfma_f32_16x16x32_bf16(a0, b0, acc[nt], 0, 0, 0);
            acc[nt] = __builtin_amdgcn_mfma_f32_16x16x32_bf16(a1, b1, acc[nt], 0, 0, 0);
        }
        __syncthreads();
    }
    #pragma unroll
    for (int nt = 0; nt < 4; ++nt)
        #pragma unroll
        for (int reg = 0; reg < 4; ++reg){
            int row = m0 + w * 16 + qd * 4 + reg;
            int col = n0 + nt * 16 + l15;
            out[(size_t)row * DIMM + col] = acc[nt][reg] + bo[col];
        }
}

extern "C" void kernel_launch(void* const* d_in, const int* in_sizes, int n_in,
                              void* d_out, int out_size, void* d_ws, size_t ws_size,
                              hipStream_t stream){
    const float* X  = (const float*)d_in[0];
    const float* Wq = (const float*)d_in[1];
    const float* Wk = (const float*)d_in[2];
    const float* Wv = (const float*)d_in[3];
    const float* Wr = (const float*)d_in[4];
    const float* Wo = (const float*)d_in[5];
    const float* bo = (const float*)d_in[6];
    const float* CB = (const float*)d_in[7];
    const float* PB = (const float*)d_in[8];
    float* out = (float*)d_out;
    u16* base = (u16*)d_out;   // 12,582,912 u16 slots

    // d_out scratch layout (u16 offsets):
    //   Qb   [0, 1048576)          (Oatt overlays this after attn)
    //   Kb   [1048576, 2097152)
    //   Vt   [2097152, 3145728)
    //   Wt   [3145728, 4325376)    dead after qkv; OpU overlays it:
    //   OpU  [3145728, 11534336)   8 splits x 128 bid x 128 rows x 64
    //   mpart f32 @ u16 [11534336, 11796480), lpart [11796480, 12058624)
    u16* Qb   = base;
    u16* Kb   = base + 1048576;
    u16* Vt   = base + 2097152;
    u16* Wt   = base + 3145728;
    u16* OpU  = base + 3145728;
    float* mpart = out + 5767168;
    float* lpart = out + 5898240;
    u16* Oatt = base;              // overlays Qb (dead after attn)

    unsigned char* fmtg = (unsigned char*)d_ws;
    u16* WsP = (u16*)((char*)d_ws + 4096);    // 4h x 32 x 64 bf16 = 16384 B
    u16* WsM = (u16*)((char*)d_ws + 20480);   // 16384 B

    convwt_kernel<<<dim3(288), 256, 0, stream>>>(Wq, Wk, Wv, Wt);
    fmtab_kernel<<<dim3(17), 256, 0, stream>>>(fmtg, Wr, WsP, WsM);
    qkv_kernel<<<dim3(12, 64), 256, 0, stream>>>(X, Wt, Qb, Kb, Vt);
    attn_kernel<<<dim3(32, NH, KSPLIT), 256, 0, stream>>>(Qb, Kb, Vt, WsP, WsM,
                                                          fmtg, CB, PB,
                                                          OpU, mpart, lpart);
    combine_kernel<<<dim3(128, NH), 256, 0, stream>>>(OpU, mpart, lpart, Oatt);

    // oproj in DESCENDING row order so out-writes (u16-view 3072/row) never
    // clobber Oatt rows (256/row) still to be read:
    //   [384,4096): writes start at u16 1,179,648 > Oatt end 1,048,576 — safe.
    //   [64,384):   writes [196608,..) > its own read region [16384, 98304).
    //   [0,64):     single block; reads complete before epilogue writes.
    oproj_kernel<<<dim3(24, 58), 256, 0, stream>>>(Oatt, Wo, bo, out, 384);
    oproj_kernel<<<dim3(24,  5), 256, 0, stream>>>(Oatt, Wo, bo, out, 64);
    oproj_kernel<<<dim3(24,  1), 256, 0, stream>>>(Oatt, Wo, bo, out, 0);
}